// Round 10
// baseline (671.161 us; speedup 1.0000x reference)
//
#include <hip/hip_runtime.h>

typedef float f32x4 __attribute__((ext_vector_type(4)));
typedef __bf16 bf16x8 __attribute__((ext_vector_type(8)));

#define NBIN_MAX 512
#define CH 6144

__device__ __forceinline__ unsigned short f2b(float f) {
    unsigned int x = __float_as_uint(f);
    unsigned int r = x + 0x7FFFu + ((x >> 16) & 1u);
    return (unsigned short)(r >> 16);
}
__device__ __forceinline__ float blo(unsigned int d) { return __uint_as_float(d << 16); }
__device__ __forceinline__ float bhi(unsigned int d) { return __uint_as_float(d & 0xffff0000u); }

// ---------------- fused prep: x->bf16 | W->bf16 transposed | row histogram ----------------
__global__ __launch_bounds__(256) void prep_kernel(const float* __restrict__ x, unsigned short* __restrict__ xb, int total8,
                                                   const float* __restrict__ W1, const float* __restrict__ W2,
                                                   unsigned short* __restrict__ w1t, unsigned short* __restrict__ w2t,
                                                   const int* __restrict__ er, int* __restrict__ counts, int E,
                                                   int nconv, int nhist) {
    int b = blockIdx.x, t = threadIdx.x;
    if (b < nconv) {
        int gid = b * 256 + t;
        if (gid >= total8) return;
        size_t idx = (size_t)gid * 8;
        float4 v0 = *(const float4*)(x + idx);
        float4 v1 = *(const float4*)(x + idx + 4);
        ushort4 o0, o1;
        o0.x = f2b(v0.x); o0.y = f2b(v0.y); o0.z = f2b(v0.z); o0.w = f2b(v0.w);
        o1.x = f2b(v1.x); o1.y = f2b(v1.y); o1.z = f2b(v1.z); o1.w = f2b(v1.w);
        *(ushort4*)(xb + idx) = o0;
        *(ushort4*)(xb + idx + 4) = o1;
    } else if (b < nconv + 512) {
        int gid = (b - nconv) * 256 + t;
        int which = gid >> 16;
        int idx = gid & 65535;
        int n = idx >> 8, k = idx & 255;
        const float* W = which ? W2 : W1;
        unsigned short* O = which ? w2t : w1t;
        O[n * 256 + k] = f2b(W[k * 256 + n]);
    } else {
        int e0 = (b - nconv - 512) * 256 + t;
        int step = nhist * 256;
        for (int e = e0; e < E; e += step)
            atomicAdd(&counts[er[e]], 1);
    }
}

// ---------------- scan (row_start from counts) ----------------
__global__ __launch_bounds__(256) void scan1_kernel(const int* __restrict__ counts, int* __restrict__ bsum, int N) {
    int base = blockIdx.x * 1024;
    int t = threadIdx.x, lane = t & 63, w = t >> 6;
    int s = 0;
#pragma unroll
    for (int j = 0; j < 4; ++j) {
        int idx = base + t * 4 + j;
        s += (idx < N) ? counts[idx] : 0;
    }
#pragma unroll
    for (int off = 1; off < 64; off <<= 1) s += __shfl_xor(s, off);
    __shared__ int red[4];
    if (lane == 0) red[w] = s;
    __syncthreads();
    if (t == 0) bsum[blockIdx.x] = red[0] + red[1] + red[2] + red[3];
}

// one-wave parallel scan over <=128 block sums
__global__ void scan2_kernel(int* __restrict__ bsum, int nb) {
    int lane = threadIdx.x;    // 64 threads
    int a = (lane < nb) ? bsum[lane] : 0;
    int b = (lane + 64 < nb) ? bsum[lane + 64] : 0;
    int ia = a, ib = b;
#pragma unroll
    for (int off = 1; off < 64; off <<= 1) {
        int u = __shfl_up(ia, off);
        if (lane >= off) ia += u;
    }
    int tot = __shfl(ia, 63);
#pragma unroll
    for (int off = 1; off < 64; off <<= 1) {
        int u = __shfl_up(ib, off);
        if (lane >= off) ib += u;
    }
    if (lane < nb) bsum[lane] = ia - a;
    if (lane + 64 < nb) bsum[lane + 64] = tot + ib - b;
}

// also writes bin_cursor[b]=row_start[b*256] and row_start[N]=E
__global__ __launch_bounds__(256) void scan3_kernel(const int* __restrict__ counts, const int* __restrict__ bsum,
                                                    int* __restrict__ row_start, int* __restrict__ bin_cursor, int N) {
    int base = blockIdx.x * 1024;
    int t = threadIdx.x, lane = t & 63, w = t >> 6;
    int v[4]; int s = 0;
#pragma unroll
    for (int j = 0; j < 4; ++j) {
        int idx = base + t * 4 + j;
        v[j] = (idx < N) ? counts[idx] : 0;
        s += v[j];
    }
    int sinc = s;
#pragma unroll
    for (int off = 1; off < 64; off <<= 1) {
        int u = __shfl_up(sinc, off);
        if (lane >= off) sinc += u;
    }
    __shared__ int wsum[4];
    if (lane == 63) wsum[w] = sinc;
    __syncthreads();
    int woff = 0;
    for (int i = 0; i < w; ++i) woff += wsum[i];
    int excl = bsum[blockIdx.x] + woff + (sinc - s);
#pragma unroll
    for (int j = 0; j < 4; ++j) {
        int idx = base + t * 4 + j;
        if (idx < N) {
            row_start[idx] = excl;
            if ((idx & 255) == 0) bin_cursor[idx >> 8] = excl;
        }
        excl += v[j];
        if (idx == N - 1) row_start[N] = excl;
    }
}

// ---------------- scatter pass 1: LDS-staged coarse binning (bin = row>>8) ----------------
__global__ __launch_bounds__(512) void scatter1_kernel(const int* __restrict__ er, const int* __restrict__ ec,
                                                       const float* __restrict__ ev, int* __restrict__ bin_cursor,
                                                       int2* __restrict__ cvt, int E, int nbin) {
    __shared__ int hist[NBIN_MAX];
    __shared__ int lstart[NBIN_MAX];
    __shared__ int gbase[NBIN_MAX];
    __shared__ int lcur[NBIN_MAX];
    __shared__ int2 stage[CH];
    __shared__ unsigned short binof[CH];
    __shared__ int wsum[8];

    const int t = threadIdx.x;
    const int e0 = blockIdx.x * CH;
    const int ecnt = min(CH, E - e0);

    for (int i = t; i < nbin; i += 512) hist[i] = 0;
    __syncthreads();
    for (int i = t; i < ecnt; i += 512)
        atomicAdd(&hist[er[e0 + i] >> 8], 1);
    __syncthreads();
    {
        int lane = t & 63, w = t >> 6;
        int a = (2 * t < nbin) ? hist[2 * t] : 0;
        int b2 = (2 * t + 1 < nbin) ? hist[2 * t + 1] : 0;
        int s = a + b2;
        int inc = s;
#pragma unroll
        for (int off = 1; off < 64; off <<= 1) {
            int u = __shfl_up(inc, off);
            if (lane >= off) inc += u;
        }
        if (lane == 63) wsum[w] = inc;
        __syncthreads();
        int woff = 0;
        for (int i = 0; i < w; ++i) woff += wsum[i];
        int excl = woff + inc - s;
        if (2 * t < nbin) { lstart[2 * t] = excl; lcur[2 * t] = excl; }
        if (2 * t + 1 < nbin) { lstart[2 * t + 1] = excl + a; lcur[2 * t + 1] = excl + a; }
    }
    for (int i = t; i < nbin; i += 512) {
        int h = hist[i];
        gbase[i] = h ? atomicAdd(&bin_cursor[i], h) : 0;
    }
    __syncthreads();
    for (int i = t; i < ecnt; i += 512) {
        int r = er[e0 + i], c = ec[e0 + i];
        float v = ev[e0 + i];
        int bin = r >> 8;
        int q = atomicAdd(&lcur[bin], 1);
        stage[q] = make_int2(c | ((r & 255) << 20), __float_as_int(v));
        binof[q] = (unsigned short)bin;
    }
    __syncthreads();
    for (int q = t; q < ecnt; q += 512) {
        int bin = binof[q];
        int gpos = gbase[bin] + (q - lstart[bin]);
        cvt[gpos] = stage[q];
    }
}

// ---------------- scatter pass 2: exact row sort within each 256-row bin ----------------
__global__ __launch_bounds__(256) void scatter2_kernel(const int2* __restrict__ cvt, const int* __restrict__ row_start,
                                                       int2* __restrict__ cv, int E, int N, int nbin) {
    __shared__ int lcur[256];
    const int b = blockIdx.x, t = threadIdx.x;
    const int r0 = b * 256;
    const int estart = row_start[r0];
    const int next = r0 + 256;
    const int eend = (next < N) ? row_start[next] : E;
    {
        int r = r0 + t;
        lcur[t] = (r < N) ? row_start[r] : 0;
    }
    __syncthreads();
    for (int i = estart + t; i < eend; i += 256) {
        int2 d = cvt[i];
        int lrow = d.x >> 20;
        int pos = atomicAdd(&lcur[lrow], 1);
        cv[pos] = make_int2(d.x & 0xFFFFF, d.y);
    }
}

// ---------------- SpMM + self-loop: h0 = (1+eps)*x + A@x  (bf16 out) ----------------
#define ACC4(d, v) { a0 += (v) * blo((d).x); a1 += (v) * bhi((d).x); \
                     a2 += (v) * blo((d).y); a3 += (v) * bhi((d).y); }

__global__ __launch_bounds__(256) void spmm_kernel(const unsigned short* __restrict__ xb, const int2* __restrict__ cv,
                                                   const int* __restrict__ row_start,
                                                   const float* __restrict__ epsp, unsigned short* __restrict__ h0, int N) {
    int node = blockIdx.x * 4 + (threadIdx.x >> 6);
    int lane = threadIdx.x & 63;
    if (node >= N) return;
    int start = __builtin_amdgcn_readfirstlane(row_start[node]);
    int deg   = __builtin_amdgcn_readfirstlane(row_start[node + 1]) - start;
    const char* xbb = (const char*)xb;
    int voff = lane * 8;
    float a0 = 0.f, a1 = 0.f, a2 = 0.f, a3 = 0.f;

    for (int base = 0; base < deg; base += 64) {
        int rem = deg - base; if (rem > 64) rem = 64;
        long long pk = 0;
        if (lane < rem) pk = __builtin_nontemporal_load((const long long*)(cv + start + base + lane));
        int2 my = make_int2((int)(pk & 0xffffffffLL), (int)(pk >> 32));
        int j = 0;
        for (; j + 8 <= rem; j += 8) {
            int cc0 = __builtin_amdgcn_readlane(my.x, j + 0);
            int cc1 = __builtin_amdgcn_readlane(my.x, j + 1);
            int cc2 = __builtin_amdgcn_readlane(my.x, j + 2);
            int cc3 = __builtin_amdgcn_readlane(my.x, j + 3);
            int cc4 = __builtin_amdgcn_readlane(my.x, j + 4);
            int cc5 = __builtin_amdgcn_readlane(my.x, j + 5);
            int cc6 = __builtin_amdgcn_readlane(my.x, j + 6);
            int cc7 = __builtin_amdgcn_readlane(my.x, j + 7);
            float v0 = __int_as_float(__builtin_amdgcn_readlane(my.y, j + 0));
            float v1 = __int_as_float(__builtin_amdgcn_readlane(my.y, j + 1));
            float v2 = __int_as_float(__builtin_amdgcn_readlane(my.y, j + 2));
            float v3 = __int_as_float(__builtin_amdgcn_readlane(my.y, j + 3));
            float v4 = __int_as_float(__builtin_amdgcn_readlane(my.y, j + 4));
            float v5 = __int_as_float(__builtin_amdgcn_readlane(my.y, j + 5));
            float v6 = __int_as_float(__builtin_amdgcn_readlane(my.y, j + 6));
            float v7 = __int_as_float(__builtin_amdgcn_readlane(my.y, j + 7));
            uint2 d0 = *(const uint2*)(xbb + (size_t)cc0 * 512 + voff);
            uint2 d1 = *(const uint2*)(xbb + (size_t)cc1 * 512 + voff);
            uint2 d2 = *(const uint2*)(xbb + (size_t)cc2 * 512 + voff);
            uint2 d3 = *(const uint2*)(xbb + (size_t)cc3 * 512 + voff);
            uint2 d4 = *(const uint2*)(xbb + (size_t)cc4 * 512 + voff);
            uint2 d5 = *(const uint2*)(xbb + (size_t)cc5 * 512 + voff);
            uint2 d6 = *(const uint2*)(xbb + (size_t)cc6 * 512 + voff);
            uint2 d7 = *(const uint2*)(xbb + (size_t)cc7 * 512 + voff);
            ACC4(d0, v0); ACC4(d1, v1); ACC4(d2, v2); ACC4(d3, v3);
            ACC4(d4, v4); ACC4(d5, v5); ACC4(d6, v6); ACC4(d7, v7);
        }
        for (; j < rem; ++j) {
            int cc0 = __builtin_amdgcn_readlane(my.x, j);
            float v0 = __int_as_float(__builtin_amdgcn_readlane(my.y, j));
            uint2 d0 = *(const uint2*)(xbb + (size_t)cc0 * 512 + voff);
            ACC4(d0, v0);
        }
    }

    float ep = 1.0f + epsp[0];
    uint2 xo = *(const uint2*)(xbb + (size_t)node * 512 + voff);
    unsigned int w0 = ((unsigned int)f2b(ep * blo(xo.x) + a0)) | (((unsigned int)f2b(ep * bhi(xo.x) + a1)) << 16);
    unsigned int w1 = ((unsigned int)f2b(ep * blo(xo.y) + a2)) | (((unsigned int)f2b(ep * bhi(xo.y) + a3)) << 16);
    unsigned long long ov = (unsigned long long)w0 | ((unsigned long long)w1 << 32);
    __builtin_nontemporal_store(ov, (unsigned long long*)((char*)h0 + (size_t)node * 512 + voff));
}

// ---------------- GEMM (bf16 MFMA) + bias + BN-stat accumulation ----------------
// BM=128, BN=256, BK=64, 512 thr = 8 waves (4m x 2n), wave tile 32x128.
// A: reg-staged double-buffered -> swizzled ds_write (no global_load_lds drain).
// B: NOT staged - fragments loaded direct from L2 (Wt is 128KB, resident, 782x reuse),
//    overlapping MFMA via vmcnt scheduling instead of a barrier drain.
// MODE 1 additionally applies BN1+ReLU (relu(a*y+c)) to A during staging, coef from stats.
template <int MODE>
__global__ __launch_bounds__(512, 4) void gemm_bn_kernel(const unsigned short* __restrict__ A,
                                                         const unsigned short* __restrict__ Wt,
                                                         const float* __restrict__ bias,
                                                         const float* __restrict__ statsIn,
                                                         const float* __restrict__ gIn,
                                                         const float* __restrict__ beIn,
                                                         float invN,
                                                         unsigned short* __restrict__ Y,
                                                         float* __restrict__ stats, int N) {
    __shared__ unsigned short As[128 * 64];   // 16 KB
    __shared__ float red[8][2][128];          // 8 KB
    __shared__ float cf[512];                 // 2 KB (MODE1)

    const int t = threadIdx.x, lane = t & 63, w = t >> 6;
    const int wm = w >> 1, wn = w & 1;
    const long row0 = (long)blockIdx.x * 128;

    f32x4 acc[2][8];
#pragma unroll
    for (int i = 0; i < 2; ++i)
#pragma unroll
        for (int j = 0; j < 8; ++j) acc[i][j] = (f32x4){0.f, 0.f, 0.f, 0.f};

    uint4 rA[2][2];
    const int slot = t & 7;
    const int rri[2] = { t >> 3, (t + 512) >> 3 };
#pragma unroll
    for (int i = 0; i < 2; ++i)
        rA[0][i] = *(const uint4*)(A + (row0 + rri[i]) * 256 + slot * 8);
    if (MODE == 1) {
        if (t < 256) {     // fold BN1 finalize: coef from stats
            float mean = statsIn[t] * invN;
            float var = statsIn[256 + t] * invN - mean * mean;
            float rs = rsqrtf(var + 1e-5f);
            float a = gIn[t] * rs;
            cf[t] = a;
            cf[256 + t] = beIn[t] - mean * a;
        }
        __syncthreads();   // cf visible before ks=0 transform
    }

    // B fragment base (per lane): row n varies by nf; k base = ks*64 + k2*32 + (lane>>4)*8
    const int nbase = wn * 128 + (lane & 15);
    const int kfrag = (lane >> 4) << 3;

#pragma unroll
    for (int ks = 0; ks < 4; ++ks) {
        const int p = ks & 1;
        if (ks) __syncthreads();      // all ds_reads of As done before overwrite
        // stage A(ks) into LDS (transform if MODE1)
#pragma unroll
        for (int i = 0; i < 2; ++i) {
            uint4 v = rA[p][i];
            unsigned int dw[4] = {v.x, v.y, v.z, v.w};
            unsigned int ov[4];
            if (MODE == 1) {
                int k = ks * 64 + slot * 8;
                float4 a0 = *(const float4*)(cf + k);
                float4 a1 = *(const float4*)(cf + k + 4);
                float4 c0 = *(const float4*)(cf + 256 + k);
                float4 c1 = *(const float4*)(cf + 256 + k + 4);
                float av[8] = {a0.x, a0.y, a0.z, a0.w, a1.x, a1.y, a1.z, a1.w};
                float cvf[8] = {c0.x, c0.y, c0.z, c0.w, c1.x, c1.y, c1.z, c1.w};
#pragma unroll
                for (int q = 0; q < 4; ++q) {
                    float o0 = fmaxf(0.f, blo(dw[q]) * av[2 * q] + cvf[2 * q]);
                    float o1 = fmaxf(0.f, bhi(dw[q]) * av[2 * q + 1] + cvf[2 * q + 1]);
                    ov[q] = (unsigned int)f2b(o0) | ((unsigned int)f2b(o1) << 16);
                }
            } else {
#pragma unroll
                for (int q = 0; q < 4; ++q) ov[q] = dw[q];
            }
            uint4 ovv = {ov[0], ov[1], ov[2], ov[3]};
            int r = rri[i];
            *(uint4*)((char*)As + r * 128 + ((slot << 4) ^ ((r & 7) << 4))) = ovv;
        }
        __syncthreads();              // As(ks) visible
        if (ks < 3) {                 // prefetch next A regs; overlaps MFMA below
#pragma unroll
            for (int i = 0; i < 2; ++i)
                rA[p ^ 1][i] = *(const uint4*)(A + (row0 + rri[i]) * 256 + (ks + 1) * 64 + slot * 8);
        }
#pragma unroll
        for (int k2 = 0; k2 < 2; ++k2) {
            int cb = k2 * 64 + ((lane >> 4) << 4);
            bf16x8 af[2];
#pragma unroll
            for (int mf = 0; mf < 2; ++mf) {
                int r = wm * 32 + mf * 16 + (lane & 15);
                af[mf] = *(const bf16x8*)((const char*)As + r * 128 + (cb ^ ((r & 7) << 4)));
            }
            const unsigned short* bp = Wt + ks * 64 + k2 * 32 + kfrag;
            // two batches of 4 B-fragments direct from L2, MFMA overlaps loads
#pragma unroll
            for (int h = 0; h < 2; ++h) {
                bf16x8 bfr[4];
#pragma unroll
                for (int u = 0; u < 4; ++u) {
                    int n = nbase + (h * 4 + u) * 16;
                    bfr[u] = *(const bf16x8*)(bp + n * 256);
                }
#pragma unroll
                for (int u = 0; u < 4; ++u) {
                    int nf = h * 4 + u;
                    acc[0][nf] = __builtin_amdgcn_mfma_f32_16x16x32_bf16(af[0], bfr[u], acc[0][nf], 0, 0, 0);
                    acc[1][nf] = __builtin_amdgcn_mfma_f32_16x16x32_bf16(af[1], bfr[u], acc[1][nf], 0, 0, 0);
                }
            }
        }
    }

    float csum[8], csq[8];
#pragma unroll
    for (int nf = 0; nf < 8; ++nf) { csum[nf] = 0.f; csq[nf] = 0.f; }
#pragma unroll
    for (int nf = 0; nf < 8; ++nf) {
        int col = wn * 128 + nf * 16 + (lane & 15);
        float b = bias[col];
#pragma unroll
        for (int mf = 0; mf < 2; ++mf) {
#pragma unroll
            for (int reg = 0; reg < 4; ++reg) {
                long r = row0 + wm * 32 + mf * 16 + ((lane >> 4) << 2) + reg;
                if (r < N) {
                    float y = acc[mf][nf][reg] + b;
                    Y[r * 256 + col] = f2b(y);
                    csum[nf] += y;
                    csq[nf] += y * y;
                }
            }
        }
    }
#pragma unroll
    for (int nf = 0; nf < 8; ++nf) {
        csum[nf] += __shfl_xor(csum[nf], 16);
        csum[nf] += __shfl_xor(csum[nf], 32);
        csq[nf] += __shfl_xor(csq[nf], 16);
        csq[nf] += __shfl_xor(csq[nf], 32);
    }
    if (lane < 16) {
#pragma unroll
        for (int nf = 0; nf < 8; ++nf) {
            red[w][0][nf * 16 + lane] = csum[nf];
            red[w][1][nf * 16 + lane] = csq[nf];
        }
    }
    __syncthreads();
    if (t < 256) {
        int wnc = t >> 7, cc = t & 127;
        float s = 0.f, q = 0.f;
#pragma unroll
        for (int m = 0; m < 4; ++m) {
            s += red[m * 2 + wnc][0][cc];
            q += red[m * 2 + wnc][1][cc];
        }
        atomicAdd(&stats[t], s);
        atomicAdd(&stats[256 + t], q);
    }
}

// ---------------- BN2 apply + ReLU, f32 output; coef computed in-block from stats ----------------
__global__ __launch_bounds__(256) void bnrelu_out_kernel(const unsigned short* __restrict__ y,
                                                         const float* __restrict__ statsIn,
                                                         const float* __restrict__ gIn,
                                                         const float* __restrict__ beIn,
                                                         float invN,
                                                         float* __restrict__ out, int total) {
    __shared__ float cf[512];
    int t = threadIdx.x;
    {
        float mean = statsIn[t] * invN;
        float var = statsIn[256 + t] * invN - mean * mean;
        float rs = rsqrtf(var + 1e-5f);
        float a = gIn[t] * rs;
        cf[t] = a;
        cf[256 + t] = beIn[t] - mean * a;
    }
    __syncthreads();
    int gid = blockIdx.x * 256 + t;
    if (gid >= total) return;
    int r = gid >> 5, s = gid & 31;
    size_t idx = (size_t)r * 256 + s * 8;
    uint4 v = *(const uint4*)(y + idx);
    float4 a0 = *(const float4*)(cf + s * 8);
    float4 a1 = *(const float4*)(cf + s * 8 + 4);
    float4 c0 = *(const float4*)(cf + 256 + s * 8);
    float4 c1 = *(const float4*)(cf + 256 + s * 8 + 4);
    unsigned int vv[4] = {v.x, v.y, v.z, v.w};
    float av[8] = {a0.x, a0.y, a0.z, a0.w, a1.x, a1.y, a1.z, a1.w};
    float cvf[8] = {c0.x, c0.y, c0.z, c0.w, c1.x, c1.y, c1.z, c1.w};
    float o[8];
#pragma unroll
    for (int j = 0; j < 4; ++j) {
        o[2 * j]     = fmaxf(0.f, blo(vv[j]) * av[2 * j] + cvf[2 * j]);
        o[2 * j + 1] = fmaxf(0.f, bhi(vv[j]) * av[2 * j + 1] + cvf[2 * j + 1]);
    }
    float4 w0 = {o[0], o[1], o[2], o[3]};
    float4 w1 = {o[4], o[5], o[6], o[7]};
    *(float4*)(out + idx) = w0;
    *(float4*)(out + idx + 4) = w1;
}

extern "C" void kernel_launch(void* const* d_in, const int* in_sizes, int n_in,
                              void* d_out, int out_size, void* d_ws, size_t ws_size,
                              hipStream_t stream) {
    const float* x   = (const float*)d_in[0];
    const int*   er  = (const int*)d_in[1];
    const int*   ec  = (const int*)d_in[2];
    const float* ev  = (const float*)d_in[3];
    const float* eps = (const float*)d_in[4];
    const float* W1  = (const float*)d_in[5];
    const float* b1  = (const float*)d_in[6];
    const float* g1  = (const float*)d_in[7];
    const float* be1 = (const float*)d_in[8];
    const float* W2  = (const float*)d_in[9];
    const float* b2  = (const float*)d_in[10];
    const float* g2  = (const float*)d_in[11];
    const float* be2 = (const float*)d_in[12];

    const int N = in_sizes[0] / 256;      // 100000
    const int E = in_sizes[1];            // 3200000
    const int Npad = ((N + 127) / 128) * 128;
    const int nbin = (N + 255) >> 8;      // 391

    char* ws = (char*)d_ws;
    size_t off = 0;
    auto alloc = [&](size_t bytes) { size_t cur = off; off = (off + bytes + 255) & ~(size_t)255; return cur; };
    size_t o_counts = alloc((size_t)N * 4);
    size_t o_stats  = alloc(4096);
    size_t zbytes   = off;                 // zero counts+stats each call
    size_t o_rowst  = alloc((size_t)(N + 1) * 4);
    size_t o_bsum   = alloc(1024);
    size_t o_binc   = alloc(NBIN_MAX * 4);
    size_t o_cv     = alloc((size_t)E * 8);
    size_t o_xb     = alloc((size_t)N * 256 * 2);
    size_t o_h0     = alloc((size_t)Npad * 256 * 2);
    size_t o_y1     = alloc((size_t)Npad * 256 * 2);   // aliases cvt (scatter temp)
    size_t o_w1t    = alloc(65536 * 2);
    size_t o_w2t    = alloc(65536 * 2);
    (void)ws_size;

    int* counts = (int*)(ws + o_counts);
    float* stats = (float*)(ws + o_stats);
    int* row_start = (int*)(ws + o_rowst);
    int* bsum = (int*)(ws + o_bsum);
    int* bin_cursor = (int*)(ws + o_binc);
    int2* cv = (int2*)(ws + o_cv);
    unsigned short* xb = (unsigned short*)(ws + o_xb);
    unsigned short* h0 = (unsigned short*)(ws + o_h0);
    unsigned short* y1 = (unsigned short*)(ws + o_y1);
    int2* cvt = (int2*)(ws + o_y1);
    unsigned short* w1t = (unsigned short*)(ws + o_w1t);
    unsigned short* w2t = (unsigned short*)(ws + o_w2t);

    hipMemsetAsync(ws, 0, zbytes, stream);

    int total8 = N * 32;
    int nconv = (total8 + 255) / 256;
    int nhist = 2048;
    prep_kernel<<<nconv + 512 + nhist, 256, 0, stream>>>(x, xb, total8, W1, W2, w1t, w2t,
                                                         er, counts, E, nconv, nhist);

    int nb = (N + 1023) / 1024;
    scan1_kernel<<<nb, 256, 0, stream>>>(counts, bsum, N);
    scan2_kernel<<<1, 64, 0, stream>>>(bsum, nb);
    scan3_kernel<<<nb, 256, 0, stream>>>(counts, bsum, row_start, bin_cursor, N);

    scatter1_kernel<<<(E + CH - 1) / CH, 512, 0, stream>>>(er, ec, ev, bin_cursor, cvt, E, nbin);
    scatter2_kernel<<<nbin, 256, 0, stream>>>(cvt, row_start, cv, E, N, nbin);

    spmm_kernel<<<(N + 3) / 4, 256, 0, stream>>>(xb, cv, row_start, eps, h0, N);

    float invN = 1.0f / (float)N;
    gemm_bn_kernel<0><<<Npad / 128, 512, 0, stream>>>(h0, w1t, b1, nullptr, nullptr, nullptr, 0.f,
                                                      y1, stats, N);
    gemm_bn_kernel<1><<<Npad / 128, 512, 0, stream>>>(y1, w2t, b2, stats, g1, be1, invN,
                                                      h0, stats + 512, N);
    bnrelu_out_kernel<<<(total8 + 255) / 256, 256, 0, stream>>>(h0, stats + 512, g2, be2, invN,
                                                                (float*)d_out, total8);
}

// Round 11
// 584.018 us; speedup vs baseline: 1.1492x; 1.1492x over previous
//
#include <hip/hip_runtime.h>

typedef float f32x4 __attribute__((ext_vector_type(4)));
typedef __bf16 bf16x8 __attribute__((ext_vector_type(8)));

#define NBIN_MAX 512
#define CH 6144

__device__ __forceinline__ unsigned short f2b(float f) {
    unsigned int x = __float_as_uint(f);
    unsigned int r = x + 0x7FFFu + ((x >> 16) & 1u);
    return (unsigned short)(r >> 16);
}
__device__ __forceinline__ float blo(unsigned int d) { return __uint_as_float(d << 16); }
__device__ __forceinline__ float bhi(unsigned int d) { return __uint_as_float(d & 0xffff0000u); }

__device__ __forceinline__ void gload_lds16(const void* g, void* l) {
    __builtin_amdgcn_global_load_lds((const __attribute__((address_space(1))) void*)g,
                                     (__attribute__((address_space(3))) void*)l, 16, 0, 0);
}

// ---------------- fused prep: x->bf16 | W->bf16 transposed | row histogram ----------------
__global__ __launch_bounds__(256) void prep_kernel(const float* __restrict__ x, unsigned short* __restrict__ xb, int total8,
                                                   const float* __restrict__ W1, const float* __restrict__ W2,
                                                   unsigned short* __restrict__ w1t, unsigned short* __restrict__ w2t,
                                                   const int* __restrict__ er, int* __restrict__ counts, int E,
                                                   int nconv, int nhist) {
    int b = blockIdx.x, t = threadIdx.x;
    if (b < nconv) {
        int gid = b * 256 + t;
        if (gid >= total8) return;
        size_t idx = (size_t)gid * 8;
        float4 v0 = *(const float4*)(x + idx);
        float4 v1 = *(const float4*)(x + idx + 4);
        ushort4 o0, o1;
        o0.x = f2b(v0.x); o0.y = f2b(v0.y); o0.z = f2b(v0.z); o0.w = f2b(v0.w);
        o1.x = f2b(v1.x); o1.y = f2b(v1.y); o1.z = f2b(v1.z); o1.w = f2b(v1.w);
        *(ushort4*)(xb + idx) = o0;
        *(ushort4*)(xb + idx + 4) = o1;
    } else if (b < nconv + 512) {
        int gid = (b - nconv) * 256 + t;
        int which = gid >> 16;
        int idx = gid & 65535;
        int n = idx >> 8, k = idx & 255;
        const float* W = which ? W2 : W1;
        unsigned short* O = which ? w2t : w1t;
        O[n * 256 + k] = f2b(W[k * 256 + n]);
    } else {
        int e0 = (b - nconv - 512) * 256 + t;
        int step = nhist * 256;
        for (int e = e0; e < E; e += step)
            atomicAdd(&counts[er[e]], 1);
    }
}

// ---------------- scan (row_start from counts) ----------------
__global__ __launch_bounds__(256) void scan1_kernel(const int* __restrict__ counts, int* __restrict__ bsum, int N) {
    int base = blockIdx.x * 1024;
    int t = threadIdx.x, lane = t & 63, w = t >> 6;
    int s = 0;
#pragma unroll
    for (int j = 0; j < 4; ++j) {
        int idx = base + t * 4 + j;
        s += (idx < N) ? counts[idx] : 0;
    }
#pragma unroll
    for (int off = 1; off < 64; off <<= 1) s += __shfl_xor(s, off);
    __shared__ int red[4];
    if (lane == 0) red[w] = s;
    __syncthreads();
    if (t == 0) bsum[blockIdx.x] = red[0] + red[1] + red[2] + red[3];
}

// one-wave parallel scan over <=128 block sums
__global__ void scan2_kernel(int* __restrict__ bsum, int nb) {
    int lane = threadIdx.x;    // 64 threads
    int a = (lane < nb) ? bsum[lane] : 0;
    int b = (lane + 64 < nb) ? bsum[lane + 64] : 0;
    int ia = a, ib = b;
#pragma unroll
    for (int off = 1; off < 64; off <<= 1) {
        int u = __shfl_up(ia, off);
        if (lane >= off) ia += u;
    }
    int tot = __shfl(ia, 63);
#pragma unroll
    for (int off = 1; off < 64; off <<= 1) {
        int u = __shfl_up(ib, off);
        if (lane >= off) ib += u;
    }
    if (lane < nb) bsum[lane] = ia - a;
    if (lane + 64 < nb) bsum[lane + 64] = tot + ib - b;
}

// also writes bin_cursor[b]=row_start[b*256] and row_start[N]=E
__global__ __launch_bounds__(256) void scan3_kernel(const int* __restrict__ counts, const int* __restrict__ bsum,
                                                    int* __restrict__ row_start, int* __restrict__ bin_cursor, int N) {
    int base = blockIdx.x * 1024;
    int t = threadIdx.x, lane = t & 63, w = t >> 6;
    int v[4]; int s = 0;
#pragma unroll
    for (int j = 0; j < 4; ++j) {
        int idx = base + t * 4 + j;
        v[j] = (idx < N) ? counts[idx] : 0;
        s += v[j];
    }
    int sinc = s;
#pragma unroll
    for (int off = 1; off < 64; off <<= 1) {
        int u = __shfl_up(sinc, off);
        if (lane >= off) sinc += u;
    }
    __shared__ int wsum[4];
    if (lane == 63) wsum[w] = sinc;
    __syncthreads();
    int woff = 0;
    for (int i = 0; i < w; ++i) woff += wsum[i];
    int excl = bsum[blockIdx.x] + woff + (sinc - s);
#pragma unroll
    for (int j = 0; j < 4; ++j) {
        int idx = base + t * 4 + j;
        if (idx < N) {
            row_start[idx] = excl;
            if ((idx & 255) == 0) bin_cursor[idx >> 8] = excl;
        }
        excl += v[j];
        if (idx == N - 1) row_start[N] = excl;
    }
}

// ---------------- scatter pass 1: LDS-staged coarse binning (bin = row>>8) ----------------
__global__ __launch_bounds__(512) void scatter1_kernel(const int* __restrict__ er, const int* __restrict__ ec,
                                                       const float* __restrict__ ev, int* __restrict__ bin_cursor,
                                                       int2* __restrict__ cvt, int E, int nbin) {
    __shared__ int hist[NBIN_MAX];
    __shared__ int lstart[NBIN_MAX];
    __shared__ int gbase[NBIN_MAX];
    __shared__ int lcur[NBIN_MAX];
    __shared__ int2 stage[CH];
    __shared__ unsigned short binof[CH];
    __shared__ int wsum[8];

    const int t = threadIdx.x;
    const int e0 = blockIdx.x * CH;
    const int ecnt = min(CH, E - e0);

    for (int i = t; i < nbin; i += 512) hist[i] = 0;
    __syncthreads();
    for (int i = t; i < ecnt; i += 512)
        atomicAdd(&hist[er[e0 + i] >> 8], 1);
    __syncthreads();
    {
        int lane = t & 63, w = t >> 6;
        int a = (2 * t < nbin) ? hist[2 * t] : 0;
        int b2 = (2 * t + 1 < nbin) ? hist[2 * t + 1] : 0;
        int s = a + b2;
        int inc = s;
#pragma unroll
        for (int off = 1; off < 64; off <<= 1) {
            int u = __shfl_up(inc, off);
            if (lane >= off) inc += u;
        }
        if (lane == 63) wsum[w] = inc;
        __syncthreads();
        int woff = 0;
        for (int i = 0; i < w; ++i) woff += wsum[i];
        int excl = woff + inc - s;
        if (2 * t < nbin) { lstart[2 * t] = excl; lcur[2 * t] = excl; }
        if (2 * t + 1 < nbin) { lstart[2 * t + 1] = excl + a; lcur[2 * t + 1] = excl + a; }
    }
    for (int i = t; i < nbin; i += 512) {
        int h = hist[i];
        gbase[i] = h ? atomicAdd(&bin_cursor[i], h) : 0;
    }
    __syncthreads();
    for (int i = t; i < ecnt; i += 512) {
        int r = er[e0 + i], c = ec[e0 + i];
        float v = ev[e0 + i];
        int bin = r >> 8;
        int q = atomicAdd(&lcur[bin], 1);
        stage[q] = make_int2(c | ((r & 255) << 20), __float_as_int(v));
        binof[q] = (unsigned short)bin;
    }
    __syncthreads();
    for (int q = t; q < ecnt; q += 512) {
        int bin = binof[q];
        int gpos = gbase[bin] + (q - lstart[bin]);
        cvt[gpos] = stage[q];
    }
}

// ---------------- scatter pass 2: exact row sort within each 256-row bin ----------------
__global__ __launch_bounds__(256) void scatter2_kernel(const int2* __restrict__ cvt, const int* __restrict__ row_start,
                                                       int2* __restrict__ cv, int E, int N, int nbin) {
    __shared__ int lcur[256];
    const int b = blockIdx.x, t = threadIdx.x;
    const int r0 = b * 256;
    const int estart = row_start[r0];
    const int next = r0 + 256;
    const int eend = (next < N) ? row_start[next] : E;
    {
        int r = r0 + t;
        lcur[t] = (r < N) ? row_start[r] : 0;
    }
    __syncthreads();
    for (int i = estart + t; i < eend; i += 256) {
        int2 d = cvt[i];
        int lrow = d.x >> 20;
        int pos = atomicAdd(&lcur[lrow], 1);
        cv[pos] = make_int2(d.x & 0xFFFFF, d.y);
    }
}

// ---------------- SpMM + self-loop, feature-split: pass HALF covers 256B half-rows ----------------
// Per pass, working set = 25.6 MB (vs 51.2) -> higher per-XCD L2 hit rate on the gather.
// Lanes 0-31 process edge j, lanes 32-63 edge j+1 (8B/lane = 512B/instr); shfl_xor(32) reduce.
template <int HALF>
__global__ __launch_bounds__(256) void spmm_half_kernel(const unsigned short* __restrict__ xb, const int2* __restrict__ cv,
                                                        const int* __restrict__ row_start,
                                                        const float* __restrict__ epsp, unsigned short* __restrict__ h0, int N) {
    int node = blockIdx.x * 4 + (threadIdx.x >> 6);
    int lane = threadIdx.x & 63;
    if (node >= N) return;
    int start = __builtin_amdgcn_readfirstlane(row_start[node]);
    int deg   = __builtin_amdgcn_readfirstlane(row_start[node + 1]) - start;
    const char* xbb = (const char*)xb;
    const int half = lane >> 5;
    const int voff = (lane & 31) * 8 + HALF * 256;
    float a0 = 0.f, a1 = 0.f, a2 = 0.f, a3 = 0.f;

#define PAIR(j0)                                                                 \
    {                                                                            \
        int cA = __builtin_amdgcn_readlane(my.x, (j0));                          \
        int cB = __builtin_amdgcn_readlane(my.x, (j0) + 1);                      \
        float vA = __int_as_float(__builtin_amdgcn_readlane(my.y, (j0)));        \
        float vB = __int_as_float(__builtin_amdgcn_readlane(my.y, (j0) + 1));    \
        int col = half ? cB : cA;                                                \
        float val = half ? vB : vA;                                              \
        uint2 d = *(const uint2*)(xbb + (size_t)col * 512 + voff);               \
        a0 += val * blo(d.x); a1 += val * bhi(d.x);                              \
        a2 += val * blo(d.y); a3 += val * bhi(d.y);                              \
    }

    for (int base = 0; base < deg; base += 64) {
        int rem = deg - base; if (rem > 64) rem = 64;
        long long pk = 0;
        if (lane < rem) pk = __builtin_nontemporal_load((const long long*)(cv + start + base + lane));
        int2 my = make_int2((int)(pk & 0xffffffffLL), (int)(pk >> 32));
        int j = 0;
        for (; j + 8 <= rem; j += 8) { PAIR(j); PAIR(j + 2); PAIR(j + 4); PAIR(j + 6); }
        for (; j < rem; j += 2) PAIR(j);   // tail: lanes >= rem hold (col=0,val=0) -> adds 0
    }
#undef PAIR

    a0 += __shfl_xor(a0, 32);
    a1 += __shfl_xor(a1, 32);
    a2 += __shfl_xor(a2, 32);
    a3 += __shfl_xor(a3, 32);

    if (lane < 32) {
        float ep = 1.0f + epsp[0];
        uint2 xo = *(const uint2*)(xbb + (size_t)node * 512 + voff);
        unsigned int w0 = ((unsigned int)f2b(ep * blo(xo.x) + a0)) | (((unsigned int)f2b(ep * bhi(xo.x) + a1)) << 16);
        unsigned int w1 = ((unsigned int)f2b(ep * blo(xo.y) + a2)) | (((unsigned int)f2b(ep * bhi(xo.y) + a3)) << 16);
        unsigned long long ov = (unsigned long long)w0 | ((unsigned long long)w1 << 32);
        __builtin_nontemporal_store(ov, (unsigned long long*)((char*)h0 + (size_t)node * 512 + voff));
    }
}

// ---------------- GEMM (bf16 MFMA) + bias + BN-stat accumulation (R8 structure) ----------------
// BM=128, BN=256, BK=64, 512 thr = 8 waves (4m x 2n), wave tile 32x128.
// MODE 0: A staged via global_load_lds (pre-swizzled source).
// MODE 1: A reg-staged, fused BN1+ReLU transform; coef computed in-block from stats (LDS).
template <int MODE>
__global__ __launch_bounds__(512, 4) void gemm_bn_kernel(const unsigned short* __restrict__ A,
                                                         const unsigned short* __restrict__ Wt,
                                                         const float* __restrict__ bias,
                                                         const float* __restrict__ statsIn,
                                                         const float* __restrict__ gIn,
                                                         const float* __restrict__ beIn,
                                                         float invN,
                                                         unsigned short* __restrict__ Y,
                                                         float* __restrict__ stats, int N) {
    __shared__ unsigned short As[128 * 64];
    __shared__ unsigned short Bs[256 * 64];
    __shared__ float red[8][2][128];
    __shared__ float cf[512];

    const int t = threadIdx.x, lane = t & 63, w = t >> 6;
    const int wm = w >> 1, wn = w & 1;
    const long row0 = (long)blockIdx.x * 128;

    f32x4 acc[2][8];
#pragma unroll
    for (int i = 0; i < 2; ++i)
#pragma unroll
        for (int j = 0; j < 8; ++j) acc[i][j] = (f32x4){0.f, 0.f, 0.f, 0.f};

    const int lr8 = lane >> 3;
    const int sb8 = (lane & 7) << 4;

    uint4 rA[2][2];
    const int slot = t & 7;
    const int rri[2] = { t >> 3, (t + 512) >> 3 };
    if (MODE == 1) {
        if (t < 256) {     // fold BN1 finalize: coef from stats
            float mean = statsIn[t] * invN;
            float var = statsIn[256 + t] * invN - mean * mean;
            float rs = rsqrtf(var + 1e-5f);
            float a = gIn[t] * rs;
            cf[t] = a;
            cf[256 + t] = beIn[t] - mean * a;
        }
#pragma unroll
        for (int i = 0; i < 2; ++i)
            rA[0][i] = *(const uint4*)(A + (row0 + rri[i]) * 256 + slot * 8);
        __syncthreads();
    }

#pragma unroll
    for (int ks = 0; ks < 4; ++ks) {
        if (ks) __syncthreads();
        if (MODE == 0) {
#pragma unroll
            for (int i = 0; i < 2; ++i) {
                int chunk = w * 2 + i;
                int r = chunk * 8 + lr8;
                int sb = sb8 ^ ((r & 7) << 4);
                gload_lds16(A + (row0 + r) * 256 + ks * 64 + (sb >> 1), (char*)As + chunk * 1024);
            }
        }
#pragma unroll
        for (int i = 0; i < 4; ++i) {
            int chunk = w * 4 + i;
            int n = chunk * 8 + lr8;
            int sb = sb8 ^ ((n & 7) << 4);
            gload_lds16(Wt + n * 256 + ks * 64 + (sb >> 1), (char*)Bs + chunk * 1024);
        }
        if (MODE == 1) {
            int k = ks * 64 + slot * 8;
            float4 a0 = *(const float4*)(cf + k);
            float4 a1 = *(const float4*)(cf + k + 4);
            float4 c0 = *(const float4*)(cf + 256 + k);
            float4 c1 = *(const float4*)(cf + 256 + k + 4);
            float av[8] = {a0.x, a0.y, a0.z, a0.w, a1.x, a1.y, a1.z, a1.w};
            float cvf[8] = {c0.x, c0.y, c0.z, c0.w, c1.x, c1.y, c1.z, c1.w};
#pragma unroll
            for (int i = 0; i < 2; ++i) {
                uint4 v = rA[ks & 1][i];
                unsigned int dw[4] = {v.x, v.y, v.z, v.w};
                unsigned int ov[4];
#pragma unroll
                for (int q = 0; q < 4; ++q) {
                    float o0 = fmaxf(0.f, blo(dw[q]) * av[2 * q] + cvf[2 * q]);
                    float o1 = fmaxf(0.f, bhi(dw[q]) * av[2 * q + 1] + cvf[2 * q + 1]);
                    ov[q] = (unsigned int)f2b(o0) | ((unsigned int)f2b(o1) << 16);
                }
                uint4 ovv = {ov[0], ov[1], ov[2], ov[3]};
                int r = rri[i];
                *(uint4*)((char*)As + r * 128 + ((slot << 4) ^ ((r & 7) << 4))) = ovv;
            }
        }
        __syncthreads();
        if (MODE == 1 && ks < 3) {
#pragma unroll
            for (int i = 0; i < 2; ++i)
                rA[(ks + 1) & 1][i] = *(const uint4*)(A + (row0 + rri[i]) * 256 + (ks + 1) * 64 + slot * 8);
        }
#pragma unroll
        for (int k2 = 0; k2 < 2; ++k2) {
            int cb = k2 * 64 + ((lane >> 4) << 4);
            bf16x8 af[2];
#pragma unroll
            for (int mf = 0; mf < 2; ++mf) {
                int r = wm * 32 + mf * 16 + (lane & 15);
                af[mf] = *(const bf16x8*)((const char*)As + r * 128 + (cb ^ ((r & 7) << 4)));
            }
#pragma unroll
            for (int nf = 0; nf < 8; ++nf) {
                int n = wn * 128 + nf * 16 + (lane & 15);
                bf16x8 bfr = *(const bf16x8*)((const char*)Bs + n * 128 + (cb ^ ((n & 7) << 4)));
                acc[0][nf] = __builtin_amdgcn_mfma_f32_16x16x32_bf16(af[0], bfr, acc[0][nf], 0, 0, 0);
                acc[1][nf] = __builtin_amdgcn_mfma_f32_16x16x32_bf16(af[1], bfr, acc[1][nf], 0, 0, 0);
            }
        }
    }

    float csum[8], csq[8];
#pragma unroll
    for (int nf = 0; nf < 8; ++nf) { csum[nf] = 0.f; csq[nf] = 0.f; }
#pragma unroll
    for (int nf = 0; nf < 8; ++nf) {
        int col = wn * 128 + nf * 16 + (lane & 15);
        float b = bias[col];
#pragma unroll
        for (int mf = 0; mf < 2; ++mf) {
#pragma unroll
            for (int reg = 0; reg < 4; ++reg) {
                long r = row0 + wm * 32 + mf * 16 + ((lane >> 4) << 2) + reg;
                if (r < N) {
                    float y = acc[mf][nf][reg] + b;
                    Y[r * 256 + col] = f2b(y);
                    csum[nf] += y;
                    csq[nf] += y * y;
                }
            }
        }
    }
#pragma unroll
    for (int nf = 0; nf < 8; ++nf) {
        csum[nf] += __shfl_xor(csum[nf], 16);
        csum[nf] += __shfl_xor(csum[nf], 32);
        csq[nf] += __shfl_xor(csq[nf], 16);
        csq[nf] += __shfl_xor(csq[nf], 32);
    }
    if (lane < 16) {
#pragma unroll
        for (int nf = 0; nf < 8; ++nf) {
            red[w][0][nf * 16 + lane] = csum[nf];
            red[w][1][nf * 16 + lane] = csq[nf];
        }
    }
    __syncthreads();
    if (t < 256) {
        int wnc = t >> 7, cc = t & 127;
        float s = 0.f, q = 0.f;
#pragma unroll
        for (int m = 0; m < 4; ++m) {
            s += red[m * 2 + wnc][0][cc];
            q += red[m * 2 + wnc][1][cc];
        }
        atomicAdd(&stats[t], s);
        atomicAdd(&stats[256 + t], q);
    }
}

// ---------------- BN2 apply + ReLU, f32 output; coef computed in-block from stats ----------------
__global__ __launch_bounds__(256) void bnrelu_out_kernel(const unsigned short* __restrict__ y,
                                                         const float* __restrict__ statsIn,
                                                         const float* __restrict__ gIn,
                                                         const float* __restrict__ beIn,
                                                         float invN,
                                                         float* __restrict__ out, int total) {
    __shared__ float cf[512];
    int t = threadIdx.x;
    {
        float mean = statsIn[t] * invN;
        float var = statsIn[256 + t] * invN - mean * mean;
        float rs = rsqrtf(var + 1e-5f);
        float a = gIn[t] * rs;
        cf[t] = a;
        cf[256 + t] = beIn[t] - mean * a;
    }
    __syncthreads();
    int gid = blockIdx.x * 256 + t;
    if (gid >= total) return;
    int r = gid >> 5, s = gid & 31;
    size_t idx = (size_t)r * 256 + s * 8;
    uint4 v = *(const uint4*)(y + idx);
    float4 a0 = *(const float4*)(cf + s * 8);
    float4 a1 = *(const float4*)(cf + s * 8 + 4);
    float4 c0 = *(const float4*)(cf + 256 + s * 8);
    float4 c1 = *(const float4*)(cf + 256 + s * 8 + 4);
    unsigned int vv[4] = {v.x, v.y, v.z, v.w};
    float av[8] = {a0.x, a0.y, a0.z, a0.w, a1.x, a1.y, a1.z, a1.w};
    float cvf[8] = {c0.x, c0.y, c0.z, c0.w, c1.x, c1.y, c1.z, c1.w};
    float o[8];
#pragma unroll
    for (int j = 0; j < 4; ++j) {
        o[2 * j]     = fmaxf(0.f, blo(vv[j]) * av[2 * j] + cvf[2 * j]);
        o[2 * j + 1] = fmaxf(0.f, bhi(vv[j]) * av[2 * j + 1] + cvf[2 * j + 1]);
    }
    float4 w0 = {o[0], o[1], o[2], o[3]};
    float4 w1 = {o[4], o[5], o[6], o[7]};
    *(float4*)(out + idx) = w0;
    *(float4*)(out + idx + 4) = w1;
}

extern "C" void kernel_launch(void* const* d_in, const int* in_sizes, int n_in,
                              void* d_out, int out_size, void* d_ws, size_t ws_size,
                              hipStream_t stream) {
    const float* x   = (const float*)d_in[0];
    const int*   er  = (const int*)d_in[1];
    const int*   ec  = (const int*)d_in[2];
    const float* ev  = (const float*)d_in[3];
    const float* eps = (const float*)d_in[4];
    const float* W1  = (const float*)d_in[5];
    const float* b1  = (const float*)d_in[6];
    const float* g1  = (const float*)d_in[7];
    const float* be1 = (const float*)d_in[8];
    const float* W2  = (const float*)d_in[9];
    const float* b2  = (const float*)d_in[10];
    const float* g2  = (const float*)d_in[11];
    const float* be2 = (const float*)d_in[12];

    const int N = in_sizes[0] / 256;      // 100000
    const int E = in_sizes[1];            // 3200000
    const int Npad = ((N + 127) / 128) * 128;
    const int nbin = (N + 255) >> 8;      // 391

    char* ws = (char*)d_ws;
    size_t off = 0;
    auto alloc = [&](size_t bytes) { size_t cur = off; off = (off + bytes + 255) & ~(size_t)255; return cur; };
    size_t o_counts = alloc((size_t)N * 4);
    size_t o_stats  = alloc(4096);
    size_t zbytes   = off;                 // zero counts+stats each call
    size_t o_rowst  = alloc((size_t)(N + 1) * 4);
    size_t o_bsum   = alloc(1024);
    size_t o_binc   = alloc(NBIN_MAX * 4);
    size_t o_cv     = alloc((size_t)E * 8);
    size_t o_xb     = alloc((size_t)N * 256 * 2);
    size_t o_h0     = alloc((size_t)Npad * 256 * 2);
    size_t o_y1     = alloc((size_t)Npad * 256 * 2);   // aliases cvt (scatter temp)
    size_t o_w1t    = alloc(65536 * 2);
    size_t o_w2t    = alloc(65536 * 2);
    (void)ws_size;

    int* counts = (int*)(ws + o_counts);
    float* stats = (float*)(ws + o_stats);
    int* row_start = (int*)(ws + o_rowst);
    int* bsum = (int*)(ws + o_bsum);
    int* bin_cursor = (int*)(ws + o_binc);
    int2* cv = (int2*)(ws + o_cv);
    unsigned short* xb = (unsigned short*)(ws + o_xb);
    unsigned short* h0 = (unsigned short*)(ws + o_h0);
    unsigned short* y1 = (unsigned short*)(ws + o_y1);
    int2* cvt = (int2*)(ws + o_y1);
    unsigned short* w1t = (unsigned short*)(ws + o_w1t);
    unsigned short* w2t = (unsigned short*)(ws + o_w2t);

    hipMemsetAsync(ws, 0, zbytes, stream);

    int total8 = N * 32;
    int nconv = (total8 + 255) / 256;
    int nhist = 2048;
    prep_kernel<<<nconv + 512 + nhist, 256, 0, stream>>>(x, xb, total8, W1, W2, w1t, w2t,
                                                         er, counts, E, nconv, nhist);

    int nb = (N + 1023) / 1024;
    scan1_kernel<<<nb, 256, 0, stream>>>(counts, bsum, N);
    scan2_kernel<<<1, 64, 0, stream>>>(bsum, nb);
    scan3_kernel<<<nb, 256, 0, stream>>>(counts, bsum, row_start, bin_cursor, N);

    scatter1_kernel<<<(E + CH - 1) / CH, 512, 0, stream>>>(er, ec, ev, bin_cursor, cvt, E, nbin);
    scatter2_kernel<<<nbin, 256, 0, stream>>>(cvt, row_start, cv, E, N, nbin);

    spmm_half_kernel<0><<<(N + 3) / 4, 256, 0, stream>>>(xb, cv, row_start, eps, h0, N);
    spmm_half_kernel<1><<<(N + 3) / 4, 256, 0, stream>>>(xb, cv, row_start, eps, h0, N);

    float invN = 1.0f / (float)N;
    gemm_bn_kernel<0><<<Npad / 128, 512, 0, stream>>>(h0, w1t, b1, nullptr, nullptr, nullptr, 0.f,
                                                      y1, stats, N);
    gemm_bn_kernel<1><<<Npad / 128, 512, 0, stream>>>(y1, w2t, b2, stats, g1, be1, invN,
                                                      h0, stats + 512, N);
    bnrelu_out_kernel<<<(total8 + 255) / 256, 256, 0, stream>>>(h0, stats + 512, g2, be2, invN,
                                                                (float*)d_out, total8);
}

// Round 12
// 483.159 us; speedup vs baseline: 1.3891x; 1.2088x over previous
//
#include <hip/hip_runtime.h>

typedef float f32x4 __attribute__((ext_vector_type(4)));
typedef __bf16 bf16x8 __attribute__((ext_vector_type(8)));

#define NBIN_MAX 512
#define CH 6144

__device__ __forceinline__ unsigned short f2b(float f) {
    unsigned int x = __float_as_uint(f);
    unsigned int r = x + 0x7FFFu + ((x >> 16) & 1u);
    return (unsigned short)(r >> 16);
}
__device__ __forceinline__ float blo(unsigned int d) { return __uint_as_float(d << 16); }
__device__ __forceinline__ float bhi(unsigned int d) { return __uint_as_float(d & 0xffff0000u); }

__device__ __forceinline__ void gload_lds16(const void* g, void* l) {
    __builtin_amdgcn_global_load_lds((const __attribute__((address_space(1))) void*)g,
                                     (__attribute__((address_space(3))) void*)l, 16, 0, 0);
}

// ---------------- fused prep: x->bf16 | W->bf16 transposed | BIN-level histogram ----------------
__global__ __launch_bounds__(256) void prep_kernel(const float* __restrict__ x, unsigned short* __restrict__ xb, int total8,
                                                   const float* __restrict__ W1, const float* __restrict__ W2,
                                                   unsigned short* __restrict__ w1t, unsigned short* __restrict__ w2t,
                                                   const int* __restrict__ er, int* __restrict__ bin_hist, int E,
                                                   int nconv, int nhist, int nbin) {
    __shared__ int lh[NBIN_MAX];
    int b = blockIdx.x, t = threadIdx.x;
    if (b < nconv) {
        int gid = b * 256 + t;
        if (gid >= total8) return;
        size_t idx = (size_t)gid * 8;
        float4 v0 = *(const float4*)(x + idx);
        float4 v1 = *(const float4*)(x + idx + 4);
        ushort4 o0, o1;
        o0.x = f2b(v0.x); o0.y = f2b(v0.y); o0.z = f2b(v0.z); o0.w = f2b(v0.w);
        o1.x = f2b(v1.x); o1.y = f2b(v1.y); o1.z = f2b(v1.z); o1.w = f2b(v1.w);
        *(ushort4*)(xb + idx) = o0;
        *(ushort4*)(xb + idx + 4) = o1;
    } else if (b < nconv + 512) {
        int gid = (b - nconv) * 256 + t;
        int which = gid >> 16;
        int idx = gid & 65535;
        int n = idx >> 8, k = idx & 255;
        const float* W = which ? W2 : W1;
        unsigned short* O = which ? w2t : w1t;
        O[n * 256 + k] = f2b(W[k * 256 + n]);
    } else {
        // bin-level histogram: LDS first, one global atomic per (block,bin)
        for (int i = t; i < NBIN_MAX; i += 256) lh[i] = 0;
        __syncthreads();
        int e0 = (b - nconv - 512) * 256 + t;
        int step = nhist * 256;
        for (int e = e0; e < E; e += step)
            atomicAdd(&lh[er[e] >> 8], 1);
        __syncthreads();
        for (int i = t; i < nbin; i += 256) {
            int h = lh[i];
            if (h) atomicAdd(&bin_hist[i], h);
        }
    }
}

// ---------------- bin scan: bin_start/bin_cursor from bin_hist; row_start[N]=E ----------------
__global__ __launch_bounds__(512) void bin_scan_kernel(const int* __restrict__ bin_hist, int* __restrict__ bin_start,
                                                       int* __restrict__ bin_cursor, int* __restrict__ row_start,
                                                       int nbin, int N, int E) {
    __shared__ int wsum[8];
    int t = threadIdx.x, lane = t & 63, w = t >> 6;
    int v = (t < nbin) ? bin_hist[t] : 0;
    int inc = v;
#pragma unroll
    for (int off = 1; off < 64; off <<= 1) {
        int u = __shfl_up(inc, off);
        if (lane >= off) inc += u;
    }
    if (lane == 63) wsum[w] = inc;
    __syncthreads();
    int woff = 0;
    for (int i = 0; i < w; ++i) woff += wsum[i];
    int excl = woff + inc - v;
    if (t < nbin) { bin_start[t] = excl; bin_cursor[t] = excl; }
    if (t == 0) { bin_start[nbin] = E; row_start[N] = E; }
}

// ---------------- scatter pass 1: LDS-staged coarse binning (bin = row>>8) ----------------
__global__ __launch_bounds__(512) void scatter1_kernel(const int* __restrict__ er, const int* __restrict__ ec,
                                                       const float* __restrict__ ev, int* __restrict__ bin_cursor,
                                                       int2* __restrict__ cvt, int E, int nbin) {
    __shared__ int hist[NBIN_MAX];
    __shared__ int lstart[NBIN_MAX];
    __shared__ int gbase[NBIN_MAX];
    __shared__ int lcur[NBIN_MAX];
    __shared__ int2 stage[CH];
    __shared__ unsigned short binof[CH];
    __shared__ int wsum[8];

    const int t = threadIdx.x;
    const int e0 = blockIdx.x * CH;
    const int ecnt = min(CH, E - e0);

    for (int i = t; i < nbin; i += 512) hist[i] = 0;
    __syncthreads();
    for (int i = t; i < ecnt; i += 512)
        atomicAdd(&hist[er[e0 + i] >> 8], 1);
    __syncthreads();
    {
        int lane = t & 63, w = t >> 6;
        int a = (2 * t < nbin) ? hist[2 * t] : 0;
        int b2 = (2 * t + 1 < nbin) ? hist[2 * t + 1] : 0;
        int s = a + b2;
        int inc = s;
#pragma unroll
        for (int off = 1; off < 64; off <<= 1) {
            int u = __shfl_up(inc, off);
            if (lane >= off) inc += u;
        }
        if (lane == 63) wsum[w] = inc;
        __syncthreads();
        int woff = 0;
        for (int i = 0; i < w; ++i) woff += wsum[i];
        int excl = woff + inc - s;
        if (2 * t < nbin) { lstart[2 * t] = excl; lcur[2 * t] = excl; }
        if (2 * t + 1 < nbin) { lstart[2 * t + 1] = excl + a; lcur[2 * t + 1] = excl + a; }
    }
    for (int i = t; i < nbin; i += 512) {
        int h = hist[i];
        gbase[i] = h ? atomicAdd(&bin_cursor[i], h) : 0;
    }
    __syncthreads();
    for (int i = t; i < ecnt; i += 512) {
        int r = er[e0 + i], c = ec[e0 + i];
        float v = ev[e0 + i];
        int bin = r >> 8;
        int q = atomicAdd(&lcur[bin], 1);
        stage[q] = make_int2(c | ((r & 255) << 20), __float_as_int(v));
        binof[q] = (unsigned short)bin;
    }
    __syncthreads();
    for (int q = t; q < ecnt; q += 512) {
        int bin = binof[q];
        int gpos = gbase[bin] + (q - lstart[bin]);
        cvt[gpos] = stage[q];
    }
}

// ---------------- scatter pass 2: per-row hist + scan (writes row_start) + counting sort ----------------
__global__ __launch_bounds__(256) void scatter2_kernel(const int2* __restrict__ cvt, const int* __restrict__ bin_start,
                                                       int* __restrict__ row_start, int2* __restrict__ cv, int N) {
    __shared__ int lhist[256];
    __shared__ int lcur[256];
    __shared__ int wsum[4];
    const int b = blockIdx.x, t = threadIdx.x;
    const int r0 = b * 256;
    const int estart = bin_start[b];
    const int eend = bin_start[b + 1];
    lhist[t] = 0;
    __syncthreads();
    for (int i = estart + t; i < eend; i += 256)
        atomicAdd(&lhist[cvt[i].x >> 20], 1);
    __syncthreads();
    // block exclusive scan over the 256 per-row counts
    int lane = t & 63, w = t >> 6;
    int v = lhist[t];
    int inc = v;
#pragma unroll
    for (int off = 1; off < 64; off <<= 1) {
        int u = __shfl_up(inc, off);
        if (lane >= off) inc += u;
    }
    if (lane == 63) wsum[w] = inc;
    __syncthreads();
    int woff = 0;
    for (int i = 0; i < w; ++i) woff += wsum[i];
    int excl = estart + woff + inc - v;
    int r = r0 + t;
    if (r < N) row_start[r] = excl;
    lcur[t] = excl;
    __syncthreads();
    for (int i = estart + t; i < eend; i += 256) {
        int2 d = cvt[i];
        int lrow = d.x >> 20;
        int pos = atomicAdd(&lcur[lrow], 1);
        cv[pos] = make_int2(d.x & 0xFFFFF, d.y);
    }
}

// ---------------- SpMM + self-loop, feature-split: pass HALF covers 256B half-rows ----------------
template <int HALF>
__global__ __launch_bounds__(256) void spmm_half_kernel(const unsigned short* __restrict__ xb, const int2* __restrict__ cv,
                                                        const int* __restrict__ row_start,
                                                        const float* __restrict__ epsp, unsigned short* __restrict__ h0, int N) {
    int node = blockIdx.x * 4 + (threadIdx.x >> 6);
    int lane = threadIdx.x & 63;
    if (node >= N) return;
    int start = __builtin_amdgcn_readfirstlane(row_start[node]);
    int deg   = __builtin_amdgcn_readfirstlane(row_start[node + 1]) - start;
    const char* xbb = (const char*)xb;
    const int half = lane >> 5;
    const int voff = (lane & 31) * 8 + HALF * 256;
    float a0 = 0.f, a1 = 0.f, a2 = 0.f, a3 = 0.f;

#define PAIR(j0)                                                                 \
    {                                                                            \
        int cA = __builtin_amdgcn_readlane(my.x, (j0));                          \
        int cB = __builtin_amdgcn_readlane(my.x, (j0) + 1);                      \
        float vA = __int_as_float(__builtin_amdgcn_readlane(my.y, (j0)));        \
        float vB = __int_as_float(__builtin_amdgcn_readlane(my.y, (j0) + 1));    \
        int col = half ? cB : cA;                                                \
        float val = half ? vB : vA;                                              \
        uint2 d = *(const uint2*)(xbb + (size_t)col * 512 + voff);               \
        a0 += val * blo(d.x); a1 += val * bhi(d.x);                              \
        a2 += val * blo(d.y); a3 += val * bhi(d.y);                              \
    }

    for (int base = 0; base < deg; base += 64) {
        int rem = deg - base; if (rem > 64) rem = 64;
        long long pk = 0;
        if (lane < rem) pk = __builtin_nontemporal_load((const long long*)(cv + start + base + lane));
        int2 my = make_int2((int)(pk & 0xffffffffLL), (int)(pk >> 32));
        int j = 0;
        for (; j + 8 <= rem; j += 8) { PAIR(j); PAIR(j + 2); PAIR(j + 4); PAIR(j + 6); }
        for (; j < rem; j += 2) PAIR(j);
    }
#undef PAIR

    a0 += __shfl_xor(a0, 32);
    a1 += __shfl_xor(a1, 32);
    a2 += __shfl_xor(a2, 32);
    a3 += __shfl_xor(a3, 32);

    if (lane < 32) {
        float ep = 1.0f + epsp[0];
        uint2 xo = *(const uint2*)(xbb + (size_t)node * 512 + voff);
        unsigned int w0 = ((unsigned int)f2b(ep * blo(xo.x) + a0)) | (((unsigned int)f2b(ep * bhi(xo.x) + a1)) << 16);
        unsigned int w1 = ((unsigned int)f2b(ep * blo(xo.y) + a2)) | (((unsigned int)f2b(ep * bhi(xo.y) + a3)) << 16);
        unsigned long long ov = (unsigned long long)w0 | ((unsigned long long)w1 << 32);
        __builtin_nontemporal_store(ov, (unsigned long long*)((char*)h0 + (size_t)node * 512 + voff));
    }
}

// ---------------- GEMM (bf16 MFMA) + bias + BN-stat accumulation (R8 structure) ----------------
template <int MODE>
__global__ __launch_bounds__(512, 4) void gemm_bn_kernel(const unsigned short* __restrict__ A,
                                                         const unsigned short* __restrict__ Wt,
                                                         const float* __restrict__ bias,
                                                         const float* __restrict__ statsIn,
                                                         const float* __restrict__ gIn,
                                                         const float* __restrict__ beIn,
                                                         float invN,
                                                         unsigned short* __restrict__ Y,
                                                         float* __restrict__ stats, int N) {
    __shared__ unsigned short As[128 * 64];
    __shared__ unsigned short Bs[256 * 64];
    __shared__ float red[8][2][128];
    __shared__ float cf[512];

    const int t = threadIdx.x, lane = t & 63, w = t >> 6;
    const int wm = w >> 1, wn = w & 1;
    const long row0 = (long)blockIdx.x * 128;

    f32x4 acc[2][8];
#pragma unroll
    for (int i = 0; i < 2; ++i)
#pragma unroll
        for (int j = 0; j < 8; ++j) acc[i][j] = (f32x4){0.f, 0.f, 0.f, 0.f};

    const int lr8 = lane >> 3;
    const int sb8 = (lane & 7) << 4;

    uint4 rA[2][2];
    const int slot = t & 7;
    const int rri[2] = { t >> 3, (t + 512) >> 3 };
    if (MODE == 1) {
        if (t < 256) {
            float mean = statsIn[t] * invN;
            float var = statsIn[256 + t] * invN - mean * mean;
            float rs = rsqrtf(var + 1e-5f);
            float a = gIn[t] * rs;
            cf[t] = a;
            cf[256 + t] = beIn[t] - mean * a;
        }
#pragma unroll
        for (int i = 0; i < 2; ++i)
            rA[0][i] = *(const uint4*)(A + (row0 + rri[i]) * 256 + slot * 8);
        __syncthreads();
    }

#pragma unroll
    for (int ks = 0; ks < 4; ++ks) {
        if (ks) __syncthreads();
        if (MODE == 0) {
#pragma unroll
            for (int i = 0; i < 2; ++i) {
                int chunk = w * 2 + i;
                int r = chunk * 8 + lr8;
                int sb = sb8 ^ ((r & 7) << 4);
                gload_lds16(A + (row0 + r) * 256 + ks * 64 + (sb >> 1), (char*)As + chunk * 1024);
            }
        }
#pragma unroll
        for (int i = 0; i < 4; ++i) {
            int chunk = w * 4 + i;
            int n = chunk * 8 + lr8;
            int sb = sb8 ^ ((n & 7) << 4);
            gload_lds16(Wt + n * 256 + ks * 64 + (sb >> 1), (char*)Bs + chunk * 1024);
        }
        if (MODE == 1) {
            int k = ks * 64 + slot * 8;
            float4 a0 = *(const float4*)(cf + k);
            float4 a1 = *(const float4*)(cf + k + 4);
            float4 c0 = *(const float4*)(cf + 256 + k);
            float4 c1 = *(const float4*)(cf + 256 + k + 4);
            float av[8] = {a0.x, a0.y, a0.z, a0.w, a1.x, a1.y, a1.z, a1.w};
            float cvf[8] = {c0.x, c0.y, c0.z, c0.w, c1.x, c1.y, c1.z, c1.w};
#pragma unroll
            for (int i = 0; i < 2; ++i) {
                uint4 v = rA[ks & 1][i];
                unsigned int dw[4] = {v.x, v.y, v.z, v.w};
                unsigned int ov[4];
#pragma unroll
                for (int q = 0; q < 4; ++q) {
                    float o0 = fmaxf(0.f, blo(dw[q]) * av[2 * q] + cvf[2 * q]);
                    float o1 = fmaxf(0.f, bhi(dw[q]) * av[2 * q + 1] + cvf[2 * q + 1]);
                    ov[q] = (unsigned int)f2b(o0) | ((unsigned int)f2b(o1) << 16);
                }
                uint4 ovv = {ov[0], ov[1], ov[2], ov[3]};
                int r = rri[i];
                *(uint4*)((char*)As + r * 128 + ((slot << 4) ^ ((r & 7) << 4))) = ovv;
            }
        }
        __syncthreads();
        if (MODE == 1 && ks < 3) {
#pragma unroll
            for (int i = 0; i < 2; ++i)
                rA[(ks + 1) & 1][i] = *(const uint4*)(A + (row0 + rri[i]) * 256 + (ks + 1) * 64 + slot * 8);
        }
#pragma unroll
        for (int k2 = 0; k2 < 2; ++k2) {
            int cb = k2 * 64 + ((lane >> 4) << 4);
            bf16x8 af[2];
#pragma unroll
            for (int mf = 0; mf < 2; ++mf) {
                int r = wm * 32 + mf * 16 + (lane & 15);
                af[mf] = *(const bf16x8*)((const char*)As + r * 128 + (cb ^ ((r & 7) << 4)));
            }
#pragma unroll
            for (int nf = 0; nf < 8; ++nf) {
                int n = wn * 128 + nf * 16 + (lane & 15);
                bf16x8 bfr = *(const bf16x8*)((const char*)Bs + n * 128 + (cb ^ ((n & 7) << 4)));
                acc[0][nf] = __builtin_amdgcn_mfma_f32_16x16x32_bf16(af[0], bfr, acc[0][nf], 0, 0, 0);
                acc[1][nf] = __builtin_amdgcn_mfma_f32_16x16x32_bf16(af[1], bfr, acc[1][nf], 0, 0, 0);
            }
        }
    }

    float csum[8], csq[8];
#pragma unroll
    for (int nf = 0; nf < 8; ++nf) { csum[nf] = 0.f; csq[nf] = 0.f; }
#pragma unroll
    for (int nf = 0; nf < 8; ++nf) {
        int col = wn * 128 + nf * 16 + (lane & 15);
        float b = bias[col];
#pragma unroll
        for (int mf = 0; mf < 2; ++mf) {
#pragma unroll
            for (int reg = 0; reg < 4; ++reg) {
                long r = row0 + wm * 32 + mf * 16 + ((lane >> 4) << 2) + reg;
                if (r < N) {
                    float y = acc[mf][nf][reg] + b;
                    Y[r * 256 + col] = f2b(y);
                    csum[nf] += y;
                    csq[nf] += y * y;
                }
            }
        }
    }
#pragma unroll
    for (int nf = 0; nf < 8; ++nf) {
        csum[nf] += __shfl_xor(csum[nf], 16);
        csum[nf] += __shfl_xor(csum[nf], 32);
        csq[nf] += __shfl_xor(csq[nf], 16);
        csq[nf] += __shfl_xor(csq[nf], 32);
    }
    if (lane < 16) {
#pragma unroll
        for (int nf = 0; nf < 8; ++nf) {
            red[w][0][nf * 16 + lane] = csum[nf];
            red[w][1][nf * 16 + lane] = csq[nf];
        }
    }
    __syncthreads();
    if (t < 256) {
        int wnc = t >> 7, cc = t & 127;
        float s = 0.f, q = 0.f;
#pragma unroll
        for (int m = 0; m < 4; ++m) {
            s += red[m * 2 + wnc][0][cc];
            q += red[m * 2 + wnc][1][cc];
        }
        atomicAdd(&stats[t], s);
        atomicAdd(&stats[256 + t], q);
    }
}

// ---------------- BN2 apply + ReLU, f32 output; coef computed in-block from stats ----------------
__global__ __launch_bounds__(256) void bnrelu_out_kernel(const unsigned short* __restrict__ y,
                                                         const float* __restrict__ statsIn,
                                                         const float* __restrict__ gIn,
                                                         const float* __restrict__ beIn,
                                                         float invN,
                                                         float* __restrict__ out, int total) {
    __shared__ float cf[512];
    int t = threadIdx.x;
    {
        float mean = statsIn[t] * invN;
        float var = statsIn[256 + t] * invN - mean * mean;
        float rs = rsqrtf(var + 1e-5f);
        float a = gIn[t] * rs;
        cf[t] = a;
        cf[256 + t] = beIn[t] - mean * a;
    }
    __syncthreads();
    int gid = blockIdx.x * 256 + t;
    if (gid >= total) return;
    int r = gid >> 5, s = gid & 31;
    size_t idx = (size_t)r * 256 + s * 8;
    uint4 v = *(const uint4*)(y + idx);
    float4 a0 = *(const float4*)(cf + s * 8);
    float4 a1 = *(const float4*)(cf + s * 8 + 4);
    float4 c0 = *(const float4*)(cf + 256 + s * 8);
    float4 c1 = *(const float4*)(cf + 256 + s * 8 + 4);
    unsigned int vv[4] = {v.x, v.y, v.z, v.w};
    float av[8] = {a0.x, a0.y, a0.z, a0.w, a1.x, a1.y, a1.z, a1.w};
    float cvf[8] = {c0.x, c0.y, c0.z, c0.w, c1.x, c1.y, c1.z, c1.w};
    float o[8];
#pragma unroll
    for (int j = 0; j < 4; ++j) {
        o[2 * j]     = fmaxf(0.f, blo(vv[j]) * av[2 * j] + cvf[2 * j]);
        o[2 * j + 1] = fmaxf(0.f, bhi(vv[j]) * av[2 * j + 1] + cvf[2 * j + 1]);
    }
    float4 w0 = {o[0], o[1], o[2], o[3]};
    float4 w1 = {o[4], o[5], o[6], o[7]};
    *(float4*)(out + idx) = w0;
    *(float4*)(out + idx + 4) = w1;
}

extern "C" void kernel_launch(void* const* d_in, const int* in_sizes, int n_in,
                              void* d_out, int out_size, void* d_ws, size_t ws_size,
                              hipStream_t stream) {
    const float* x   = (const float*)d_in[0];
    const int*   er  = (const int*)d_in[1];
    const int*   ec  = (const int*)d_in[2];
    const float* ev  = (const float*)d_in[3];
    const float* eps = (const float*)d_in[4];
    const float* W1  = (const float*)d_in[5];
    const float* b1  = (const float*)d_in[6];
    const float* g1  = (const float*)d_in[7];
    const float* be1 = (const float*)d_in[8];
    const float* W2  = (const float*)d_in[9];
    const float* b2  = (const float*)d_in[10];
    const float* g2  = (const float*)d_in[11];
    const float* be2 = (const float*)d_in[12];

    const int N = in_sizes[0] / 256;      // 100000
    const int E = in_sizes[1];            // 3200000
    const int Npad = ((N + 127) / 128) * 128;
    const int nbin = (N + 255) >> 8;      // 391

    char* ws = (char*)d_ws;
    size_t off = 0;
    auto alloc = [&](size_t bytes) { size_t cur = off; off = (off + bytes + 255) & ~(size_t)255; return cur; };
    size_t o_stats  = alloc(4096);
    size_t o_binh   = alloc(NBIN_MAX * 4);
    size_t zbytes   = off;                 // zero stats+bin_hist each call
    size_t o_rowst  = alloc((size_t)(N + 1) * 4);
    size_t o_bins   = alloc((NBIN_MAX + 1) * 4);
    size_t o_binc   = alloc(NBIN_MAX * 4);
    size_t o_cv     = alloc((size_t)E * 8);
    size_t o_xb     = alloc((size_t)N * 256 * 2);
    size_t o_h0     = alloc((size_t)Npad * 256 * 2);
    size_t o_y1     = alloc((size_t)Npad * 256 * 2);   // aliases cvt (scatter temp)
    size_t o_w1t    = alloc(65536 * 2);
    size_t o_w2t    = alloc(65536 * 2);
    (void)ws_size;

    float* stats = (float*)(ws + o_stats);
    int* bin_hist = (int*)(ws + o_binh);
    int* row_start = (int*)(ws + o_rowst);
    int* bin_start = (int*)(ws + o_bins);
    int* bin_cursor = (int*)(ws + o_binc);
    int2* cv = (int2*)(ws + o_cv);
    unsigned short* xb = (unsigned short*)(ws + o_xb);
    unsigned short* h0 = (unsigned short*)(ws + o_h0);
    unsigned short* y1 = (unsigned short*)(ws + o_y1);
    int2* cvt = (int2*)(ws + o_y1);
    unsigned short* w1t = (unsigned short*)(ws + o_w1t);
    unsigned short* w2t = (unsigned short*)(ws + o_w2t);

    hipMemsetAsync(ws, 0, zbytes, stream);

    int total8 = N * 32;
    int nconv = (total8 + 255) / 256;
    int nhist = 256;
    prep_kernel<<<nconv + 512 + nhist, 256, 0, stream>>>(x, xb, total8, W1, W2, w1t, w2t,
                                                         er, bin_hist, E, nconv, nhist, nbin);

    bin_scan_kernel<<<1, 512, 0, stream>>>(bin_hist, bin_start, bin_cursor, row_start, nbin, N, E);

    scatter1_kernel<<<(E + CH - 1) / CH, 512, 0, stream>>>(er, ec, ev, bin_cursor, cvt, E, nbin);
    scatter2_kernel<<<nbin, 256, 0, stream>>>(cvt, bin_start, row_start, cv, N);

    spmm_half_kernel<0><<<(N + 3) / 4, 256, 0, stream>>>(xb, cv, row_start, eps, h0, N);
    spmm_half_kernel<1><<<(N + 3) / 4, 256, 0, stream>>>(xb, cv, row_start, eps, h0, N);

    float invN = 1.0f / (float)N;
    gemm_bn_kernel<0><<<Npad / 128, 512, 0, stream>>>(h0, w1t, b1, nullptr, nullptr, nullptr, 0.f,
                                                      y1, stats, N);
    gemm_bn_kernel<1><<<Npad / 128, 512, 0, stream>>>(y1, w2t, b2, stats, g1, be1, invN,
                                                      h0, stats + 512, N);
    bnrelu_out_kernel<<<(total8 + 255) / 256, 256, 0, stream>>>(h0, stats + 512, g2, be2, invN,
                                                                (float*)d_out, total8);
}

// Round 14
// 467.095 us; speedup vs baseline: 1.4369x; 1.0344x over previous
//
#include <hip/hip_runtime.h>

typedef float f32x4 __attribute__((ext_vector_type(4)));
typedef unsigned int uintx4 __attribute__((ext_vector_type(4)));
typedef __bf16 bf16x8 __attribute__((ext_vector_type(8)));

#define NBIN_MAX 512
#define CH 6144

__device__ __forceinline__ unsigned short f2b(float f) {
    unsigned int x = __float_as_uint(f);
    unsigned int r = x + 0x7FFFu + ((x >> 16) & 1u);
    return (unsigned short)(r >> 16);
}
__device__ __forceinline__ float blo(unsigned int d) { return __uint_as_float(d << 16); }
__device__ __forceinline__ float bhi(unsigned int d) { return __uint_as_float(d & 0xffff0000u); }

__device__ __forceinline__ void gload_lds16(const void* g, void* l) {
    __builtin_amdgcn_global_load_lds((const __attribute__((address_space(1))) void*)g,
                                     (__attribute__((address_space(3))) void*)l, 16, 0, 0);
}

// ---------------- fused prep: x->bf16 (nt) | W->bf16 transposed | BIN-level histogram ----------------
__global__ __launch_bounds__(256) void prep_kernel(const float* __restrict__ x, unsigned short* __restrict__ xb, int total8,
                                                   const float* __restrict__ W1, const float* __restrict__ W2,
                                                   unsigned short* __restrict__ w1t, unsigned short* __restrict__ w2t,
                                                   const int* __restrict__ er, int* __restrict__ bin_hist, int E,
                                                   int nconv, int nhist, int nbin) {
    __shared__ int lh[NBIN_MAX];
    int b = blockIdx.x, t = threadIdx.x;
    if (b < nconv) {
        int gid = b * 256 + t;
        if (gid >= total8) return;
        size_t idx = (size_t)gid * 8;
        uintx4 u0 = __builtin_nontemporal_load((const uintx4*)(x + idx));
        uintx4 u1 = __builtin_nontemporal_load((const uintx4*)(x + idx + 4));
        uintx4 o;
        o.x = (unsigned int)f2b(__uint_as_float(u0.x)) | ((unsigned int)f2b(__uint_as_float(u0.y)) << 16);
        o.y = (unsigned int)f2b(__uint_as_float(u0.z)) | ((unsigned int)f2b(__uint_as_float(u0.w)) << 16);
        o.z = (unsigned int)f2b(__uint_as_float(u1.x)) | ((unsigned int)f2b(__uint_as_float(u1.y)) << 16);
        o.w = (unsigned int)f2b(__uint_as_float(u1.z)) | ((unsigned int)f2b(__uint_as_float(u1.w)) << 16);
        __builtin_nontemporal_store(o, (uintx4*)(xb + idx));
    } else if (b < nconv + 512) {
        int gid = (b - nconv) * 256 + t;
        int which = gid >> 16;
        int idx = gid & 65535;
        int n = idx >> 8, k = idx & 255;
        const float* W = which ? W2 : W1;
        unsigned short* O = which ? w2t : w1t;
        O[n * 256 + k] = f2b(W[k * 256 + n]);
    } else {
        for (int i = t; i < NBIN_MAX; i += 256) lh[i] = 0;
        __syncthreads();
        int e0 = (b - nconv - 512) * 256 + t;
        int step = nhist * 256;
        for (int e = e0; e < E; e += step)
            atomicAdd(&lh[er[e] >> 8], 1);
        __syncthreads();
        for (int i = t; i < nbin; i += 256) {
            int h = lh[i];
            if (h) atomicAdd(&bin_hist[i], h);
        }
    }
}

// ---------------- bin scan: bin_start/bin_cursor from bin_hist; row_start[N]=E ----------------
__global__ __launch_bounds__(512) void bin_scan_kernel(const int* __restrict__ bin_hist, int* __restrict__ bin_start,
                                                       int* __restrict__ bin_cursor, int* __restrict__ row_start,
                                                       int nbin, int N, int E) {
    __shared__ int wsum[8];
    int t = threadIdx.x, lane = t & 63, w = t >> 6;
    int v = (t < nbin) ? bin_hist[t] : 0;
    int inc = v;
#pragma unroll
    for (int off = 1; off < 64; off <<= 1) {
        int u = __shfl_up(inc, off);
        if (lane >= off) inc += u;
    }
    if (lane == 63) wsum[w] = inc;
    __syncthreads();
    int woff = 0;
    for (int i = 0; i < w; ++i) woff += wsum[i];
    int excl = woff + inc - v;
    if (t < nbin) { bin_start[t] = excl; bin_cursor[t] = excl; }
    if (t == 0) { bin_start[nbin] = E; row_start[N] = E; }
}

// ---------------- scatter pass 1: LDS-staged coarse binning (bin = row>>8) ----------------
__global__ __launch_bounds__(512) void scatter1_kernel(const int* __restrict__ er, const int* __restrict__ ec,
                                                       const float* __restrict__ ev, int* __restrict__ bin_cursor,
                                                       int2* __restrict__ cvt, int E, int nbin) {
    __shared__ int hist[NBIN_MAX];
    __shared__ int lstart[NBIN_MAX];
    __shared__ int gbase[NBIN_MAX];
    __shared__ int lcur[NBIN_MAX];
    __shared__ int2 stage[CH];
    __shared__ unsigned short binof[CH];
    __shared__ int wsum[8];

    const int t = threadIdx.x;
    const int e0 = blockIdx.x * CH;
    const int ecnt = min(CH, E - e0);

    for (int i = t; i < nbin; i += 512) hist[i] = 0;
    __syncthreads();
    for (int i = t; i < ecnt; i += 512)
        atomicAdd(&hist[er[e0 + i] >> 8], 1);
    __syncthreads();
    {
        int lane = t & 63, w = t >> 6;
        int a = (2 * t < nbin) ? hist[2 * t] : 0;
        int b2 = (2 * t + 1 < nbin) ? hist[2 * t + 1] : 0;
        int s = a + b2;
        int inc = s;
#pragma unroll
        for (int off = 1; off < 64; off <<= 1) {
            int u = __shfl_up(inc, off);
            if (lane >= off) inc += u;
        }
        if (lane == 63) wsum[w] = inc;
        __syncthreads();
        int woff = 0;
        for (int i = 0; i < w; ++i) woff += wsum[i];
        int excl = woff + inc - s;
        if (2 * t < nbin) { lstart[2 * t] = excl; lcur[2 * t] = excl; }
        if (2 * t + 1 < nbin) { lstart[2 * t + 1] = excl + a; lcur[2 * t + 1] = excl + a; }
    }
    for (int i = t; i < nbin; i += 512) {
        int h = hist[i];
        gbase[i] = h ? atomicAdd(&bin_cursor[i], h) : 0;
    }
    __syncthreads();
    for (int i = t; i < ecnt; i += 512) {
        int r = er[e0 + i], c = ec[e0 + i];
        float v = ev[e0 + i];
        int bin = r >> 8;
        int q = atomicAdd(&lcur[bin], 1);
        stage[q] = make_int2(c | ((r & 255) << 20), __float_as_int(v));
        binof[q] = (unsigned short)bin;
    }
    __syncthreads();
    for (int q = t; q < ecnt; q += 512) {
        int bin = binof[q];
        int gpos = gbase[bin] + (q - lstart[bin]);
        cvt[gpos] = stage[q];
    }
}

// ---------------- scatter pass 2: per-row hist + scan (writes row_start) + counting sort ----------------
__global__ __launch_bounds__(256) void scatter2_kernel(const int2* __restrict__ cvt, const int* __restrict__ bin_start,
                                                       int* __restrict__ row_start, int2* __restrict__ cv, int N) {
    __shared__ int lhist[256];
    __shared__ int lcur[256];
    __shared__ int wsum[4];
    const int b = blockIdx.x, t = threadIdx.x;
    const int r0 = b * 256;
    const int estart = bin_start[b];
    const int eend = bin_start[b + 1];
    lhist[t] = 0;
    __syncthreads();
    for (int i = estart + t; i < eend; i += 256)
        atomicAdd(&lhist[cvt[i].x >> 20], 1);
    __syncthreads();
    int lane = t & 63, w = t >> 6;
    int v = lhist[t];
    int inc = v;
#pragma unroll
    for (int off = 1; off < 64; off <<= 1) {
        int u = __shfl_up(inc, off);
        if (lane >= off) inc += u;
    }
    if (lane == 63) wsum[w] = inc;
    __syncthreads();
    int woff = 0;
    for (int i = 0; i < w; ++i) woff += wsum[i];
    int excl = estart + woff + inc - v;
    int r = r0 + t;
    if (r < N) row_start[r] = excl;
    lcur[t] = excl;
    __syncthreads();
    for (int i = estart + t; i < eend; i += 256) {
        int2 d = cvt[i];
        int lrow = d.x >> 20;
        int pos = atomicAdd(&lcur[lrow], 1);
        cv[pos] = make_int2(d.x & 0xFFFFF, d.y);
    }
}

// ---------------- SpMM + self-loop, feature-split in one dispatch ----------------
// Blocks [0,nblk) do half 0 (bytes 0..255 of each row), [nblk,2nblk) half 1.
__global__ __launch_bounds__(256) void spmm_kernel(const unsigned short* __restrict__ xb, const int2* __restrict__ cv,
                                                   const int* __restrict__ row_start,
                                                   const float* __restrict__ epsp, unsigned short* __restrict__ h0,
                                                   int N, int nblk) {
    int bid = blockIdx.x;
    int hsel = (bid >= nblk) ? 1 : 0;
    int node = (bid - hsel * nblk) * 4 + (threadIdx.x >> 6);
    int lane = threadIdx.x & 63;
    if (node >= N) return;
    int start = __builtin_amdgcn_readfirstlane(row_start[node]);
    int deg   = __builtin_amdgcn_readfirstlane(row_start[node + 1]) - start;
    const char* xbb = (const char*)xb;
    const int half = lane >> 5;
    const int voff = (lane & 31) * 8 + hsel * 256;
    float a0 = 0.f, a1 = 0.f, a2 = 0.f, a3 = 0.f;

#define PAIR(j0)                                                                 \
    {                                                                            \
        int cA = __builtin_amdgcn_readlane(my.x, (j0));                          \
        int cB = __builtin_amdgcn_readlane(my.x, (j0) + 1);                      \
        float vA = __int_as_float(__builtin_amdgcn_readlane(my.y, (j0)));        \
        float vB = __int_as_float(__builtin_amdgcn_readlane(my.y, (j0) + 1));    \
        int col = half ? cB : cA;                                                \
        float val = half ? vB : vA;                                              \
        uint2 d = *(const uint2*)(xbb + (size_t)col * 512 + voff);               \
        a0 += val * blo(d.x); a1 += val * bhi(d.x);                              \
        a2 += val * blo(d.y); a3 += val * bhi(d.y);                              \
    }

    for (int base = 0; base < deg; base += 64) {
        int rem = deg - base; if (rem > 64) rem = 64;
        long long pk = 0;
        if (lane < rem) pk = __builtin_nontemporal_load((const long long*)(cv + start + base + lane));
        int2 my = make_int2((int)(pk & 0xffffffffLL), (int)(pk >> 32));
        int j = 0;
        for (; j + 8 <= rem; j += 8) { PAIR(j); PAIR(j + 2); PAIR(j + 4); PAIR(j + 6); }
        for (; j < rem; j += 2) PAIR(j);
    }
#undef PAIR

    a0 += __shfl_xor(a0, 32);
    a1 += __shfl_xor(a1, 32);
    a2 += __shfl_xor(a2, 32);
    a3 += __shfl_xor(a3, 32);

    if (lane < 32) {
        float ep = 1.0f + epsp[0];
        uint2 xo = *(const uint2*)(xbb + (size_t)node * 512 + voff);
        unsigned int w0 = ((unsigned int)f2b(ep * blo(xo.x) + a0)) | (((unsigned int)f2b(ep * bhi(xo.x) + a1)) << 16);
        unsigned int w1 = ((unsigned int)f2b(ep * blo(xo.y) + a2)) | (((unsigned int)f2b(ep * bhi(xo.y) + a3)) << 16);
        unsigned long long ov = (unsigned long long)w0 | ((unsigned long long)w1 << 32);
        __builtin_nontemporal_store(ov, (unsigned long long*)((char*)h0 + (size_t)node * 512 + voff));
    }
}

// ---------------- GEMM (bf16 MFMA) + bias + BN-stat accumulation ----------------
// BM=128, BN=256, BK=64, 512 thr = 8 waves (4m x 2n), wave tile 32x128.
// A: reg-staged double-buffered for BOTH modes. B: global_load_lds (pre-swizzled source).
// MODE 1 additionally applies BN1+ReLU to A during staging; coef computed from stats.
template <int MODE>
__global__ __launch_bounds__(512, 4) void gemm_bn_kernel(const unsigned short* __restrict__ A,
                                                         const unsigned short* __restrict__ Wt,
                                                         const float* __restrict__ bias,
                                                         const float* __restrict__ statsIn,
                                                         const float* __restrict__ gIn,
                                                         const float* __restrict__ beIn,
                                                         float invN,
                                                         unsigned short* __restrict__ Y,
                                                         float* __restrict__ stats, int N) {
    __shared__ unsigned short As[128 * 64];
    __shared__ unsigned short Bs[256 * 64];
    __shared__ float red[8][2][128];
    __shared__ float cf[512];

    const int t = threadIdx.x, lane = t & 63, w = t >> 6;
    const int wm = w >> 1, wn = w & 1;
    const long row0 = (long)blockIdx.x * 128;

    f32x4 acc[2][8];
#pragma unroll
    for (int i = 0; i < 2; ++i)
#pragma unroll
        for (int j = 0; j < 8; ++j) acc[i][j] = (f32x4){0.f, 0.f, 0.f, 0.f};

    const int lr8 = lane >> 3;
    const int sb8 = (lane & 7) << 4;

    uint4 rA[2][2];
    const int slot = t & 7;
    const int rri[2] = { t >> 3, (t + 512) >> 3 };
    if (MODE == 1 && t < 256) {
        float mean = statsIn[t] * invN;
        float var = statsIn[256 + t] * invN - mean * mean;
        float rs = rsqrtf(var + 1e-5f);
        float a = gIn[t] * rs;
        cf[t] = a;
        cf[256 + t] = beIn[t] - mean * a;
    }
#pragma unroll
    for (int i = 0; i < 2; ++i)
        rA[0][i] = *(const uint4*)(A + (row0 + rri[i]) * 256 + slot * 8);
    if (MODE == 1) __syncthreads();   // cf visible before ks=0 transform

#pragma unroll
    for (int ks = 0; ks < 4; ++ks) {
        const int p = ks & 1;
        if (ks) __syncthreads();
        // B tile via global_load_lds
#pragma unroll
        for (int i = 0; i < 4; ++i) {
            int chunk = w * 4 + i;
            int n = chunk * 8 + lr8;
            int sb = sb8 ^ ((n & 7) << 4);
            gload_lds16(Wt + n * 256 + ks * 64 + (sb >> 1), (char*)Bs + chunk * 1024);
        }
        // A stage from regs (transform if MODE1)
#pragma unroll
        for (int i = 0; i < 2; ++i) {
            uint4 v = rA[p][i];
            unsigned int dw[4] = {v.x, v.y, v.z, v.w};
            unsigned int ov[4];
            if (MODE == 1) {
                int k = ks * 64 + slot * 8;
                float4 a0 = *(const float4*)(cf + k);
                float4 a1 = *(const float4*)(cf + k + 4);
                float4 c0 = *(const float4*)(cf + 256 + k);
                float4 c1 = *(const float4*)(cf + 256 + k + 4);
                float av[8] = {a0.x, a0.y, a0.z, a0.w, a1.x, a1.y, a1.z, a1.w};
                float cvf[8] = {c0.x, c0.y, c0.z, c0.w, c1.x, c1.y, c1.z, c1.w};
#pragma unroll
                for (int q = 0; q < 4; ++q) {
                    float o0 = fmaxf(0.f, blo(dw[q]) * av[2 * q] + cvf[2 * q]);
                    float o1 = fmaxf(0.f, bhi(dw[q]) * av[2 * q + 1] + cvf[2 * q + 1]);
                    ov[q] = (unsigned int)f2b(o0) | ((unsigned int)f2b(o1) << 16);
                }
            } else {
#pragma unroll
                for (int q = 0; q < 4; ++q) ov[q] = dw[q];
            }
            uint4 ovv = {ov[0], ov[1], ov[2], ov[3]};
            int r = rri[i];
            *(uint4*)((char*)As + r * 128 + ((slot << 4) ^ ((r & 7) << 4))) = ovv;
        }
        __syncthreads();              // drains B gloads + A ds_writes
        if (ks < 3) {                 // prefetch next A regs; overlaps MFMA
#pragma unroll
            for (int i = 0; i < 2; ++i)
                rA[p ^ 1][i] = *(const uint4*)(A + (row0 + rri[i]) * 256 + (ks + 1) * 64 + slot * 8);
        }
#pragma unroll
        for (int k2 = 0; k2 < 2; ++k2) {
            int cb = k2 * 64 + ((lane >> 4) << 4);
            bf16x8 af[2];
#pragma unroll
            for (int mf = 0; mf < 2; ++mf) {
                int r = wm * 32 + mf * 16 + (lane & 15);
                af[mf] = *(const bf16x8*)((const char*)As + r * 128 + (cb ^ ((r & 7) << 4)));
            }
#pragma unroll
            for (int nf = 0; nf < 8; ++nf) {
                int n = wn * 128 + nf * 16 + (lane & 15);
                bf16x8 bfr = *(const bf16x8*)((const char*)Bs + n * 128 + (cb ^ ((n & 7) << 4)));
                acc[0][nf] = __builtin_amdgcn_mfma_f32_16x16x32_bf16(af[0], bfr, acc[0][nf], 0, 0, 0);
                acc[1][nf] = __builtin_amdgcn_mfma_f32_16x16x32_bf16(af[1], bfr, acc[1][nf], 0, 0, 0);
            }
        }
    }

    float csum[8], csq[8];
#pragma unroll
    for (int nf = 0; nf < 8; ++nf) { csum[nf] = 0.f; csq[nf] = 0.f; }
#pragma unroll
    for (int nf = 0; nf < 8; ++nf) {
        int col = wn * 128 + nf * 16 + (lane & 15);
        float b = bias[col];
#pragma unroll
        for (int mf = 0; mf < 2; ++mf) {
#pragma unroll
            for (int reg = 0; reg < 4; ++reg) {
                long r = row0 + wm * 32 + mf * 16 + ((lane >> 4) << 2) + reg;
                if (r < N) {
                    float y = acc[mf][nf][reg] + b;
                    Y[r * 256 + col] = f2b(y);
                    csum[nf] += y;
                    csq[nf] += y * y;
                }
            }
        }
    }
#pragma unroll
    for (int nf = 0; nf < 8; ++nf) {
        csum[nf] += __shfl_xor(csum[nf], 16);
        csum[nf] += __shfl_xor(csum[nf], 32);
        csq[nf] += __shfl_xor(csq[nf], 16);
        csq[nf] += __shfl_xor(csq[nf], 32);
    }
    if (lane < 16) {
#pragma unroll
        for (int nf = 0; nf < 8; ++nf) {
            red[w][0][nf * 16 + lane] = csum[nf];
            red[w][1][nf * 16 + lane] = csq[nf];
        }
    }
    __syncthreads();
    if (t < 256) {
        int wnc = t >> 7, cc = t & 127;
        float s = 0.f, q = 0.f;
#pragma unroll
        for (int m = 0; m < 4; ++m) {
            s += red[m * 2 + wnc][0][cc];
            q += red[m * 2 + wnc][1][cc];
        }
        atomicAdd(&stats[t], s);
        atomicAdd(&stats[256 + t], q);
    }
}

// ---------------- BN2 apply + ReLU, f32 output (nt streams); coef from stats ----------------
__global__ __launch_bounds__(256) void bnrelu_out_kernel(const unsigned short* __restrict__ y,
                                                         const float* __restrict__ statsIn,
                                                         const float* __restrict__ gIn,
                                                         const float* __restrict__ beIn,
                                                         float invN,
                                                         float* __restrict__ out, int total) {
    __shared__ float cf[512];
    int t = threadIdx.x;
    {
        float mean = statsIn[t] * invN;
        float var = statsIn[256 + t] * invN - mean * mean;
        float rs = rsqrtf(var + 1e-5f);
        float a = gIn[t] * rs;
        cf[t] = a;
        cf[256 + t] = beIn[t] - mean * a;
    }
    __syncthreads();
    int gid = blockIdx.x * 256 + t;
    if (gid >= total) return;
    int r = gid >> 5, s = gid & 31;
    size_t idx = (size_t)r * 256 + s * 8;
    uintx4 v = __builtin_nontemporal_load((const uintx4*)(y + idx));
    float4 a0 = *(const float4*)(cf + s * 8);
    float4 a1 = *(const float4*)(cf + s * 8 + 4);
    float4 c0 = *(const float4*)(cf + 256 + s * 8);
    float4 c1 = *(const float4*)(cf + 256 + s * 8 + 4);
    unsigned int vv[4] = {v.x, v.y, v.z, v.w};
    float av[8] = {a0.x, a0.y, a0.z, a0.w, a1.x, a1.y, a1.z, a1.w};
    float cvf[8] = {c0.x, c0.y, c0.z, c0.w, c1.x, c1.y, c1.z, c1.w};
    float o[8];
#pragma unroll
    for (int j = 0; j < 4; ++j) {
        o[2 * j]     = fmaxf(0.f, blo(vv[j]) * av[2 * j] + cvf[2 * j]);
        o[2 * j + 1] = fmaxf(0.f, bhi(vv[j]) * av[2 * j + 1] + cvf[2 * j + 1]);
    }
    f32x4 w0 = {o[0], o[1], o[2], o[3]};
    f32x4 w1 = {o[4], o[5], o[6], o[7]};
    __builtin_nontemporal_store(w0, (f32x4*)(out + idx));
    __builtin_nontemporal_store(w1, (f32x4*)(out + idx + 4));
}

extern "C" void kernel_launch(void* const* d_in, const int* in_sizes, int n_in,
                              void* d_out, int out_size, void* d_ws, size_t ws_size,
                              hipStream_t stream) {
    const float* x   = (const float*)d_in[0];
    const int*   er  = (const int*)d_in[1];
    const int*   ec  = (const int*)d_in[2];
    const float* ev  = (const float*)d_in[3];
    const float* eps = (const float*)d_in[4];
    const float* W1  = (const float*)d_in[5];
    const float* b1  = (const float*)d_in[6];
    const float* g1  = (const float*)d_in[7];
    const float* be1 = (const float*)d_in[8];
    const float* W2  = (const float*)d_in[9];
    const float* b2  = (const float*)d_in[10];
    const float* g2  = (const float*)d_in[11];
    const float* be2 = (const float*)d_in[12];

    const int N = in_sizes[0] / 256;      // 100000
    const int E = in_sizes[1];            // 3200000
    const int Npad = ((N + 127) / 128) * 128;
    const int nbin = (N + 255) >> 8;      // 391

    char* ws = (char*)d_ws;
    size_t off = 0;
    auto alloc = [&](size_t bytes) { size_t cur = off; off = (off + bytes + 255) & ~(size_t)255; return cur; };
    size_t o_stats  = alloc(4096);
    size_t o_binh   = alloc(NBIN_MAX * 4);
    size_t zbytes   = off;                 // zero stats+bin_hist each call
    size_t o_rowst  = alloc((size_t)(N + 1) * 4);
    size_t o_bins   = alloc((NBIN_MAX + 1) * 4);
    size_t o_binc   = alloc(NBIN_MAX * 4);
    size_t o_cv     = alloc((size_t)E * 8);
    size_t o_xb     = alloc((size_t)N * 256 * 2);
    size_t o_h0     = alloc((size_t)Npad * 256 * 2);
    size_t o_y1     = alloc((size_t)Npad * 256 * 2);   // aliases cvt (scatter temp)
    size_t o_w1t    = alloc(65536 * 2);
    size_t o_w2t    = alloc(65536 * 2);
    (void)ws_size;

    float* stats = (float*)(ws + o_stats);
    int* bin_hist = (int*)(ws + o_binh);
    int* row_start = (int*)(ws + o_rowst);
    int* bin_start = (int*)(ws + o_bins);
    int* bin_cursor = (int*)(ws + o_binc);
    int2* cv = (int2*)(ws + o_cv);
    unsigned short* xb = (unsigned short*)(ws + o_xb);
    unsigned short* h0 = (unsigned short*)(ws + o_h0);
    unsigned short* y1 = (unsigned short*)(ws + o_y1);
    int2* cvt = (int2*)(ws + o_y1);
    unsigned short* w1t = (unsigned short*)(ws + o_w1t);
    unsigned short* w2t = (unsigned short*)(ws + o_w2t);

    hipMemsetAsync(ws, 0, zbytes, stream);

    int total8 = N * 32;
    int nconv = (total8 + 255) / 256;
    int nhist = 256;
    prep_kernel<<<nconv + 512 + nhist, 256, 0, stream>>>(x, xb, total8, W1, W2, w1t, w2t,
                                                         er, bin_hist, E, nconv, nhist, nbin);

    bin_scan_kernel<<<1, 512, 0, stream>>>(bin_hist, bin_start, bin_cursor, row_start, nbin, N, E);

    scatter1_kernel<<<(E + CH - 1) / CH, 512, 0, stream>>>(er, ec, ev, bin_cursor, cvt, E, nbin);
    scatter2_kernel<<<nbin, 256, 0, stream>>>(cvt, bin_start, row_start, cv, N);

    int nblk = (N + 3) / 4;
    spmm_kernel<<<2 * nblk, 256, 0, stream>>>(xb, cv, row_start, eps, h0, N, nblk);

    float invN = 1.0f / (float)N;
    gemm_bn_kernel<0><<<Npad / 128, 512, 0, stream>>>(h0, w1t, b1, nullptr, nullptr, nullptr, 0.f,
                                                      y1, stats, N);
    gemm_bn_kernel<1><<<Npad / 128, 512, 0, stream>>>(y1, w2t, b2, stats, g1, be1, invN,
                                                      h0, stats + 512, N);
    bnrelu_out_kernel<<<(total8 + 255) / 256, 256, 0, stream>>>(h0, stats + 512, g2, be2, invN,
                                                                (float*)d_out, total8);
}